// Round 5
// baseline (868.814 us; speedup 1.0000x reference)
//
#include <hip/hip_runtime.h>
#include <hip/hip_bf16.h>
#include <math.h>

// Round 5 = Round 4 resubmitted (GPU acquisition timeout; kernel never ran).
// Round-2 MFMA pipeline + THE FIX: d_out is FLOAT32 (x f32, size f32).
// Evidence: bit-identical absmax 8.515625 across 3 different numerics rounds
// (only exact-integer `size` values are round-invariant -> they were landing
// inside the f32 x-region when written as packed u16), out_npz 11.6MB ~ f32.
// Shapes: B=8, N=1024, C=768, H=12, HD=64. r=512 => all even tokens merge.

typedef unsigned short u16;
typedef __attribute__((ext_vector_type(8))) short vshort8;   // 8 x bf16
typedef __attribute__((ext_vector_type(4))) float vfloat4;

#define DEVI __device__ __forceinline__

DEVI u16 f2bf(float f) {
  union { float f; unsigned u; } x{f};
  unsigned r = x.u + 0x7fffu + ((x.u >> 16) & 1u);
  return (u16)(r >> 16);
}

// ---------------- workspace layout (bytes) ----------------
static constexpr size_t O_QW  = 0;          // qkv_w bf16  2304*768*2 = 3538944
static constexpr size_t O_PW  = 3538944;    // proj_w bf16 768*768*2  = 1179648
static constexpr size_t O_F1W = 4718592;    // fc1_w bf16  3072*768*2 = 4718592
static constexpr size_t O_F2W = 9437184;    // fc2_w bf16  768*3072*2 = 4718592
static constexpr size_t O_WKD = 14155776;   // wk f64 (transposed [768][64]) 393216
static constexpr size_t O_A   = 14548992;   // h16 (8192*768*2) -> later xa
static constexpr size_t O_B   = 27131904;   // Q (12.58MB) -> x1 part1 -> x2
static constexpr size_t O_C   = 39714816;   // K            -> x1 part2 -> ln2q
static constexpr size_t O_D   = 52297728;   // V            -> xm
static constexpr size_t O_E   = 64880640;   // mn64 8192*64*8 = 4194304
static constexpr size_t O_G   = 69074944;   // gq bf16 4096*3072*2 = 25165824
static constexpr size_t O_IDX = 94240768;   // nidx 16384
static constexpr size_t O_SZ  = 94257152;   // szf 16384
// total = 94273536 (~89.9 MB)

// ---------------- prep: weights->bf16, wkT[c][d] = mean_h(W_k)[d][c] f64 ----------------
__global__ __launch_bounds__(256) void k_prep(
    const float* __restrict__ qkvw, const float* __restrict__ projw,
    const float* __restrict__ fc1w, const float* __restrict__ fc2w,
    u16* __restrict__ qw, u16* __restrict__ pw, u16* __restrict__ f1,
    u16* __restrict__ f2, double* __restrict__ wkT) {
  int i = blockIdx.x * 256 + threadIdx.x;
  if (i < 1769472) qw[i] = f2bf(qkvw[i]);
  else if (i < 2359296) pw[i - 1769472] = f2bf(projw[i - 1769472]);
  else if (i < 4718592) f1[i - 2359296] = f2bf(fc1w[i - 2359296]);
  else if (i < 7077888) f2[i - 4718592] = f2bf(fc2w[i - 4718592]);
  else if (i < 7127040) {
    int k = i - 7077888; int c = k >> 6, d = k & 63;
    double s = 0.0;
    #pragma unroll
    for (int h = 0; h < 12; ++h) s += (double)qkvw[(size_t)(768 + h * 64 + d) * 768 + c];
    wkT[(size_t)c * 64 + d] = s * (1.0 / 12.0);
  }
}

// ---------------- LN1 -> bf16 ----------------
__global__ __launch_bounds__(256) void k_ln1(
    const float* __restrict__ x, const float* __restrict__ g,
    const float* __restrict__ bt, u16* __restrict__ h16) {
  __shared__ float red[4];
  int row = blockIdx.x, t = threadIdx.x;
  const float* xr = x + (size_t)row * 768;
  float v0 = xr[t], v1 = xr[t + 256], v2 = xr[t + 512];
  float s = v0 + v1 + v2;
  #pragma unroll
  for (int m = 32; m >= 1; m >>= 1) s += __shfl_xor(s, m);
  if ((t & 63) == 0) red[t >> 6] = s;
  __syncthreads();
  float mu = (red[0] + red[1] + red[2] + red[3]) * (1.f / 768.f);
  float d0 = v0 - mu, d1 = v1 - mu, d2 = v2 - mu;
  float q = d0 * d0 + d1 * d1 + d2 * d2;
  #pragma unroll
  for (int m = 32; m >= 1; m >>= 1) q += __shfl_xor(q, m);
  __syncthreads();
  if ((t & 63) == 0) red[t >> 6] = q;
  __syncthreads();
  float var = (red[0] + red[1] + red[2] + red[3]) * (1.f / 768.f);
  float inv = rsqrtf(var + 1e-5f);
  u16* hq = h16 + (size_t)row * 768;
  hq[t]       = f2bf(d0 * inv * g[t] + bt[t]);
  hq[t + 256] = f2bf(d1 * inv * g[t + 256] + bt[t + 256]);
  hq[t + 512] = f2bf(d2 * inv * g[t + 512] + bt[t + 512]);
}

// ---------------- metric in f64: mn[row][d] = normalize(LN64(x) . wkT) ----------------
__global__ __launch_bounds__(256) void k_metric64(
    const float* __restrict__ x, const float* __restrict__ g,
    const float* __restrict__ bt, const double* __restrict__ wkT,
    double* __restrict__ mn) {
  __shared__ double hs[768];
  __shared__ double redd[4];
  __shared__ double part[4][64];
  int row = blockIdx.x, t = threadIdx.x;
  const float* xr = x + (size_t)row * 768;
  double v0 = xr[t], v1 = xr[t + 256], v2 = xr[t + 512];
  double s = v0 + v1 + v2;
  #pragma unroll
  for (int m = 32; m >= 1; m >>= 1) s += __shfl_xor(s, m);
  if ((t & 63) == 0) redd[t >> 6] = s;
  __syncthreads();
  double mu = (redd[0] + redd[1] + redd[2] + redd[3]) * (1.0 / 768.0);
  double d0 = v0 - mu, d1 = v1 - mu, d2 = v2 - mu;
  double q = d0 * d0 + d1 * d1 + d2 * d2;
  #pragma unroll
  for (int m = 32; m >= 1; m >>= 1) q += __shfl_xor(q, m);
  __syncthreads();
  if ((t & 63) == 0) redd[t >> 6] = q;
  __syncthreads();
  double var = (redd[0] + redd[1] + redd[2] + redd[3]) * (1.0 / 768.0);
  double inv = 1.0 / sqrt(var + 1e-5);
  hs[t]       = d0 * inv * (double)g[t] + (double)bt[t];
  hs[t + 256] = d1 * inv * (double)g[t + 256] + (double)bt[t + 256];
  hs[t + 512] = d2 * inv * (double)g[t + 512] + (double)bt[t + 512];
  __syncthreads();
  int d = t & 63, pr = t >> 6;
  double acc = 0.0;
  const double* hp = hs + pr * 192;
  const double* wp = wkT + (size_t)(pr * 192) * 64 + d;
  for (int c = 0; c < 192; ++c) acc += hp[c] * wp[(size_t)c * 64];
  part[pr][d] = acc;
  __syncthreads();
  if (t < 64) {
    double m = part[0][t] + part[1][t] + part[2][t] + part[3][t];
    double ss = m * m;
    #pragma unroll
    for (int msk = 32; msk >= 1; msk >>= 1) ss += __shfl_xor(ss, msk);
    mn[(size_t)row * 64 + t] = m / sqrt(ss);
  }
}

// ---------------- ToMe argmax (f64) ----------------
__global__ __launch_bounds__(64) void k_scores(
    const double* __restrict__ mn, int* __restrict__ nidx) {
  __shared__ double bs[32][65];
  int blk = blockIdx.x; int b = blk >> 3, chunk = blk & 7;
  int t = threadIdx.x;
  int i = chunk * 64 + t;
  const double* ar = mn + ((size_t)b * 1024 + 2 * i) * 64;
  double a[64];
  #pragma unroll
  for (int c = 0; c < 64; ++c) a[c] = ar[c];
  double best = -1e300; int bestj = 0;
  for (int j0 = 0; j0 < 512; j0 += 32) {
    __syncthreads();
    for (int q = 0; q < 32; ++q) {
      bs[q][t] = mn[((size_t)b * 1024 + 2 * (j0 + q) + 1) * 64 + t];
    }
    __syncthreads();
    for (int jj = 0; jj < 32; ++jj) {
      double dv = 0.0;
      #pragma unroll
      for (int c = 0; c < 64; ++c) dv += a[c] * bs[jj][c];
      if (dv > best) { best = dv; bestj = j0 + jj; }  // ascending scan = first max
    }
  }
  nidx[b * 512 + i] = bestj;
}

// ---------------- bf16 MFMA GEMM, 128x128 tile, BK=64, padded-LDS reg staging ----------
// C[M,N] = A[M,K] @ B[N,K]^T ; EPI: 0=qkv scatter, 1=proj(+bias+resid->f32),
// 2=fc1(+bias,gelu->bf16), 3=fc2(+bias+resid->f32 d_out)
template <int EPI>
__global__ __launch_bounds__(256) void k_gemm(
    const u16* __restrict__ A, const u16* __restrict__ Bw,
    int M, int N, int K,
    const float* __restrict__ bias, const float* __restrict__ resid,
    u16* __restrict__ o0, u16* __restrict__ o1, u16* __restrict__ o2,
    float* __restrict__ of) {
  __shared__ u16 As[128 * 72];
  __shared__ u16 Bs[128 * 72];
  const int tid = threadIdx.x, lane = tid & 63, wid = tid >> 6;
  const int bm = blockIdx.x, bn = blockIdx.y;
  const int wm = wid >> 1, wn = wid & 1;
  vfloat4 acc[4][4];
  #pragma unroll
  for (int i = 0; i < 4; ++i)
    #pragma unroll
    for (int j = 0; j < 4; ++j) acc[i][j] = (vfloat4){0.f, 0.f, 0.f, 0.f};

  for (int kt = 0; kt < K; kt += 64) {
    vshort8 ra[4], rb[4];
    #pragma unroll
    for (int q = 0; q < 4; ++q) {
      int idx = q * 256 + tid; int r = idx >> 3, ck = idx & 7;
      ra[q] = *(const vshort8*)&A[(size_t)(bm * 128 + r) * K + kt + ck * 8];
      rb[q] = *(const vshort8*)&Bw[(size_t)(bn * 128 + r) * K + kt + ck * 8];
    }
    __syncthreads();
    #pragma unroll
    for (int q = 0; q < 4; ++q) {
      int idx = q * 256 + tid; int r = idx >> 3, ck = idx & 7;
      *(vshort8*)&As[r * 72 + ck * 8] = ra[q];
      *(vshort8*)&Bs[r * 72 + ck * 8] = rb[q];
    }
    __syncthreads();
    #pragma unroll
    for (int kc = 0; kc < 2; ++kc) {
      vshort8 av[4], bv[4];
      #pragma unroll
      for (int i = 0; i < 4; ++i) {
        int ra_ = wm * 64 + i * 16 + (lane & 15);
        av[i] = *(const vshort8*)&As[ra_ * 72 + (kc * 4 + (lane >> 4)) * 8];
      }
      #pragma unroll
      for (int i = 0; i < 4; ++i) {
        int rb_ = wn * 64 + i * 16 + (lane & 15);
        bv[i] = *(const vshort8*)&Bs[rb_ * 72 + (kc * 4 + (lane >> 4)) * 8];
      }
      #pragma unroll
      for (int mi = 0; mi < 4; ++mi)
        #pragma unroll
        for (int ni = 0; ni < 4; ++ni)
          acc[mi][ni] = __builtin_amdgcn_mfma_f32_16x16x32_bf16(av[mi], bv[ni], acc[mi][ni], 0, 0, 0);
    }
    __syncthreads();
  }

  const int rq = lane >> 4;
  #pragma unroll
  for (int mi = 0; mi < 4; ++mi) {
    #pragma unroll
    for (int ni = 0; ni < 4; ++ni) {
      #pragma unroll
      for (int r = 0; r < 4; ++r) {
        int row = bm * 128 + wm * 64 + mi * 16 + rq * 4 + r;
        int col = bn * 128 + wn * 64 + ni * 16 + (lane & 15);
        float v = acc[mi][ni][r];
        if constexpr (EPI == 0) {
          int mat = col / 768, rem = col % 768;
          int head = rem >> 6, d = rem & 63;
          int b = row >> 10, tok = row & 1023;
          u16* dst = (mat == 0) ? o0 : ((mat == 1) ? o1 : o2);
          dst[(((size_t)b * 12 + head) * 1024 + tok) * 64 + d] = f2bf(v);
        } else if constexpr (EPI == 1) {
          v += bias[col] + resid[(size_t)row * N + col];
          of[(size_t)row * N + col] = v;
        } else if constexpr (EPI == 2) {
          v += bias[col];
          v = 0.5f * v * (1.f + erff(v * 0.70710678118654752f));   // exact GELU
          o0[(size_t)row * N + col] = f2bf(v);
        } else {
          v += bias[col] + resid[(size_t)row * N + col];
          of[(size_t)row * N + col] = v;                 // f32 final output
        }
      }
    }
  }
}

// ---------------- flash attention, padded LDS, explicit barriers ----------------
__global__ __launch_bounds__(256) void k_attn(
    const u16* __restrict__ Qb, const u16* __restrict__ Kb,
    const u16* __restrict__ Vb, const float* __restrict__ asz,
    u16* __restrict__ xa) {
  __shared__ u16 Ks[64 * 72];
  __shared__ u16 Vt[64 * 72];
  __shared__ u16 Pl[4][16 * 72];
  __shared__ float la[64];
  int blk = blockIdx.x;
  int qt = blk & 15, h = (blk >> 4) % 12, b = blk / 192;
  int t = threadIdx.x, lane = t & 63, wid = t >> 6;
  const size_t bh = (size_t)b * 12 + h;
  const u16* Qp = Qb + (bh * 1024 + qt * 64 + wid * 16 + (lane & 15)) * 64;
  vshort8 qa0 = *(const vshort8*)(Qp + (lane >> 4) * 8);
  vshort8 qa1 = *(const vshort8*)(Qp + 32 + (lane >> 4) * 8);
  vfloat4 accO[4];
  #pragma unroll
  for (int i = 0; i < 4; ++i) accO[i] = (vfloat4){0.f, 0.f, 0.f, 0.f};
  float mrow[4], lrow[4];
  #pragma unroll
  for (int r = 0; r < 4; ++r) { mrow[r] = -INFINITY; lrow[r] = 0.f; }

  for (int j0 = 0; j0 < 1024; j0 += 64) {
    vshort8 kr[2];
    #pragma unroll
    for (int q = 0; q < 2; ++q) {
      int idx = q * 256 + t; int r = idx >> 3, ck = idx & 7;
      kr[q] = *(const vshort8*)&Kb[(bh * 1024 + j0 + r) * 64 + ck * 8];
    }
    int jj = t & 63, d0 = (t >> 6) * 16;
    const u16* vp = Vb + (bh * 1024 + j0 + jj) * 64 + d0;
    vshort8 v0 = *(const vshort8*)vp;
    vshort8 v1 = *(const vshort8*)(vp + 8);
    float lv = 0.f;
    if (t < 64) lv = asz[(size_t)b * 1024 + j0 + t];
    __syncthreads();                       // prior tile's LDS reads complete
    #pragma unroll
    for (int q = 0; q < 2; ++q) {
      int idx = q * 256 + t; int r = idx >> 3, ck = idx & 7;
      *(vshort8*)&Ks[r * 72 + ck * 8] = kr[q];
    }
    #pragma unroll
    for (int e = 0; e < 8; ++e) {
      Vt[(d0 + e) * 72 + jj] = (u16)v0[e];
      Vt[(d0 + 8 + e) * 72 + jj] = (u16)v1[e];
    }
    if (t < 64) la[t] = logf(lv);
    __syncthreads();

    vfloat4 sacc[4];
    #pragma unroll
    for (int jt = 0; jt < 4; ++jt) {
      int r = jt * 16 + (lane & 15);
      vshort8 kb0 = *(const vshort8*)&Ks[r * 72 + (lane >> 4) * 8];
      vshort8 kb1 = *(const vshort8*)&Ks[r * 72 + (4 + (lane >> 4)) * 8];
      vfloat4 z = (vfloat4){0.f, 0.f, 0.f, 0.f};
      z = __builtin_amdgcn_mfma_f32_16x16x32_bf16(qa0, kb0, z, 0, 0, 0);
      z = __builtin_amdgcn_mfma_f32_16x16x32_bf16(qa1, kb1, z, 0, 0, 0);
      sacc[jt] = z;
    }
    float mnew[4], fsc[4];
    #pragma unroll
    for (int r = 0; r < 4; ++r) {
      float mt = -INFINITY;
      #pragma unroll
      for (int jt = 0; jt < 4; ++jt) {
        float sv = sacc[jt][r] * 0.125f + la[jt * 16 + (lane & 15)];
        sacc[jt][r] = sv;
        mt = fmaxf(mt, sv);
      }
      mt = fmaxf(mt, __shfl_xor(mt, 1)); mt = fmaxf(mt, __shfl_xor(mt, 2));
      mt = fmaxf(mt, __shfl_xor(mt, 4)); mt = fmaxf(mt, __shfl_xor(mt, 8));
      mnew[r] = fmaxf(mrow[r], mt);
      fsc[r] = expf(mrow[r] - mnew[r]);
      mrow[r] = mnew[r];
    }
    float psum[4] = {0.f, 0.f, 0.f, 0.f};
    #pragma unroll
    for (int jt = 0; jt < 4; ++jt) {
      #pragma unroll
      for (int r = 0; r < 4; ++r) {
        float p = expf(sacc[jt][r] - mnew[r]);
        psum[r] += p;
        int q = (lane >> 4) * 4 + r;
        int j = jt * 16 + (lane & 15);
        Pl[wid][q * 72 + j] = f2bf(p);
      }
    }
    #pragma unroll
    for (int r = 0; r < 4; ++r) {
      float sv = psum[r];
      sv += __shfl_xor(sv, 1); sv += __shfl_xor(sv, 2);
      sv += __shfl_xor(sv, 4); sv += __shfl_xor(sv, 8);
      lrow[r] = lrow[r] * fsc[r] + sv;
    }
    __syncthreads();                       // P visible before PV reads
    #pragma unroll
    for (int dt = 0; dt < 4; ++dt)
      #pragma unroll
      for (int r = 0; r < 4; ++r) accO[dt][r] *= fsc[r];
    #pragma unroll
    for (int jc = 0; jc < 2; ++jc) {
      vshort8 pa = *(const vshort8*)&Pl[wid][(lane & 15) * 72 + (jc * 4 + (lane >> 4)) * 8];
      #pragma unroll
      for (int dt = 0; dt < 4; ++dt) {
        vshort8 vb8 = *(const vshort8*)&Vt[(dt * 16 + (lane & 15)) * 72 + (jc * 4 + (lane >> 4)) * 8];
        accO[dt] = __builtin_amdgcn_mfma_f32_16x16x32_bf16(pa, vb8, accO[dt], 0, 0, 0);
      }
    }
  }
  #pragma unroll
  for (int r = 0; r < 4; ++r) {
    float invl = 1.f / lrow[r];
    int row = qt * 64 + wid * 16 + (lane >> 4) * 4 + r;
    #pragma unroll
    for (int dt = 0; dt < 4; ++dt) {
      int col = h * 64 + dt * 16 + (lane & 15);
      xa[((size_t)b * 1024 + row) * 768 + col] = f2bf(accO[dt][r] * invl);
    }
  }
}

// ---------------- merge ----------------
__global__ __launch_bounds__(256) void k_merge_init(
    const float* __restrict__ x1, const float* __restrict__ asz,
    float* __restrict__ xm, float* __restrict__ szf) {
  int row = blockIdx.x;                 // b*512 + j
  int b = row >> 9, j = row & 511;
  size_t srow = (size_t)b * 1024 + 2 * j + 1;
  float s = asz[srow];
  const float* xp = x1 + srow * 768;
  float* op = xm + (size_t)row * 768;
  for (int c4 = threadIdx.x; c4 < 192; c4 += 256) {
    vfloat4 v = *(const vfloat4*)&xp[c4 * 4];
    v *= s;
    *(vfloat4*)&op[c4 * 4] = v;
  }
  if (threadIdx.x == 0) szf[row] = s;
}

__global__ __launch_bounds__(256) void k_merge_scatter(
    const float* __restrict__ x1, const float* __restrict__ asz,
    const int* __restrict__ nidx, float* __restrict__ xm, float* __restrict__ szf) {
  int row = blockIdx.x;                 // b*512 + i
  int b = row >> 9;
  int dst = nidx[row];
  size_t srow = (size_t)b * 1024 + 2 * (row & 511);
  float s = asz[srow];
  const float* xp = x1 + srow * 768;
  float* op = xm + ((size_t)b * 512 + dst) * 768;
  for (int c = threadIdx.x; c < 768; c += 256) atomicAdd(&op[c], xp[c] * s);
  if (threadIdx.x == 0) atomicAdd(&szf[b * 512 + dst], s);
}

// ---------------- x2 = xm/size; LN2 -> bf16; size -> d_out tail (f32) ----------------
__global__ __launch_bounds__(256) void k_ln2div(
    const float* __restrict__ xm, const float* __restrict__ szf,
    const float* __restrict__ g, const float* __restrict__ bt,
    float* __restrict__ x2, u16* __restrict__ ln2q, float* __restrict__ szo) {
  __shared__ float red[4];
  int row = blockIdx.x, t = threadIdx.x;
  float inv = 1.f / szf[row];
  const float* xp = xm + (size_t)row * 768;
  float v0 = xp[t] * inv, v1 = xp[t + 256] * inv, v2 = xp[t + 512] * inv;
  float* xo = x2 + (size_t)row * 768;
  xo[t] = v0; xo[t + 256] = v1; xo[t + 512] = v2;
  float s = v0 + v1 + v2;
  #pragma unroll
  for (int m = 32; m >= 1; m >>= 1) s += __shfl_xor(s, m);
  if ((t & 63) == 0) red[t >> 6] = s;
  __syncthreads();
  float mu = (red[0] + red[1] + red[2] + red[3]) * (1.f / 768.f);
  float d0 = v0 - mu, d1 = v1 - mu, d2 = v2 - mu;
  float q = d0 * d0 + d1 * d1 + d2 * d2;
  #pragma unroll
  for (int m = 32; m >= 1; m >>= 1) q += __shfl_xor(q, m);
  __syncthreads();
  if ((t & 63) == 0) red[t >> 6] = q;
  __syncthreads();
  float var = (red[0] + red[1] + red[2] + red[3]) * (1.f / 768.f);
  float is = rsqrtf(var + 1e-5f);
  u16* lo = ln2q + (size_t)row * 768;
  lo[t]       = f2bf(d0 * is * g[t] + bt[t]);
  lo[t + 256] = f2bf(d1 * is * g[t + 256] + bt[t + 256]);
  lo[t + 512] = f2bf(d2 * is * g[t + 512] + bt[t + 512]);
  if (t == 0) szo[row] = szf[row];
}

// ---------------- launch ----------------
extern "C" void kernel_launch(void* const* d_in, const int* in_sizes, int n_in,
                              void* d_out, int out_size, void* d_ws, size_t ws_size,
                              hipStream_t stream) {
  (void)in_sizes; (void)n_in; (void)out_size; (void)ws_size;
  const float* x    = (const float*)d_in[0];
  const float* asz  = (const float*)d_in[1];
  const float* ln1w = (const float*)d_in[2];
  const float* ln1b = (const float*)d_in[3];
  const float* qkvw = (const float*)d_in[4];
  const float* projw= (const float*)d_in[5];
  const float* projb= (const float*)d_in[6];
  const float* ln2w = (const float*)d_in[7];
  const float* ln2b = (const float*)d_in[8];
  const float* fc1w = (const float*)d_in[9];
  const float* fc1b = (const float*)d_in[10];
  const float* fc2w = (const float*)d_in[11];
  const float* fc2b = (const float*)d_in[12];

  char* ws = (char*)d_ws;
  u16*    qw   = (u16*)(ws + O_QW);
  u16*    pw   = (u16*)(ws + O_PW);
  u16*    f1w_ = (u16*)(ws + O_F1W);
  u16*    f2w_ = (u16*)(ws + O_F2W);
  double* wkT  = (double*)(ws + O_WKD);
  u16*    h16  = (u16*)(ws + O_A);
  u16*    xab  = (u16*)(ws + O_A);          // reuse: h16 dead after qkv GEMM
  u16*    Qb   = (u16*)(ws + O_B);
  u16*    Kb   = (u16*)(ws + O_C);
  u16*    Vb   = (u16*)(ws + O_D);
  double* mn   = (double*)(ws + O_E);
  float*  x1   = (float*)(ws + O_B);        // reuse: Q,K dead after attn (25.2MB)
  float*  xm   = (float*)(ws + O_D);        // reuse: V dead after attn
  float*  x2   = (float*)(ws + O_B);        // reuse: x1 dead after scatter
  u16*    ln2q = (u16*)(ws + O_C);          // reuse: x1 dead after scatter
  u16*    gq   = (u16*)(ws + O_G);
  int*    nidx = (int*)(ws + O_IDX);
  float*  szf  = (float*)(ws + O_SZ);

  float* outf = (float*)d_out;              // f32 output: x then size
  float* szo  = outf + 3145728;

  k_prep<<<27841, 256, 0, stream>>>(qkvw, projw, fc1w, fc2w, qw, pw, f1w_, f2w_, wkT);
  k_ln1<<<8192, 256, 0, stream>>>(x, ln1w, ln1b, h16);
  k_metric64<<<8192, 256, 0, stream>>>(x, ln1w, ln1b, wkT, mn);
  k_scores<<<64, 64, 0, stream>>>(mn, nidx);
  k_gemm<0><<<dim3(64, 18), 256, 0, stream>>>(h16, qw, 8192, 2304, 768,
      nullptr, nullptr, Qb, Kb, Vb, nullptr);
  k_attn<<<1536, 256, 0, stream>>>(Qb, Kb, Vb, asz, xab);
  k_gemm<1><<<dim3(64, 6), 256, 0, stream>>>(xab, pw, 8192, 768, 768,
      projb, x, nullptr, nullptr, nullptr, x1);
  k_merge_init<<<4096, 256, 0, stream>>>(x1, asz, xm, szf);
  k_merge_scatter<<<4096, 256, 0, stream>>>(x1, asz, nidx, xm, szf);
  k_ln2div<<<4096, 256, 0, stream>>>(xm, szf, ln2w, ln2b, x2, ln2q, szo);
  k_gemm<2><<<dim3(32, 24), 256, 0, stream>>>(ln2q, f1w_, 4096, 3072, 768,
      fc1b, nullptr, gq, nullptr, nullptr, nullptr);
  k_gemm<3><<<dim3(32, 6), 256, 0, stream>>>(gq, f2w_, 4096, 768, 3072,
      fc2b, x2, nullptr, nullptr, nullptr, outf);
}

// Round 6
// 761.304 us; speedup vs baseline: 1.1412x; 1.1412x over previous
//
#include <hip/hip_runtime.h>
#include <hip/hip_bf16.h>
#include <math.h>

// Round 6: baseline passed (868us, absmax 0.031). Single change this round:
// k_scores was 254us at 0.74% occupancy (64 waves on 256 CUs, serial f64
// chains). Re-gridded to 4096 blocks (one per (b,i)), 4-way split
// accumulators, wave-level (v,j) argmax reduce with first-max tie-break.
// Everything else identical to the passing round-5 kernel.

typedef unsigned short u16;
typedef __attribute__((ext_vector_type(8))) short vshort8;   // 8 x bf16
typedef __attribute__((ext_vector_type(4))) float vfloat4;

#define DEVI __device__ __forceinline__

DEVI u16 f2bf(float f) {
  union { float f; unsigned u; } x{f};
  unsigned r = x.u + 0x7fffu + ((x.u >> 16) & 1u);
  return (u16)(r >> 16);
}

// ---------------- workspace layout (bytes) ----------------
static constexpr size_t O_QW  = 0;          // qkv_w bf16  2304*768*2 = 3538944
static constexpr size_t O_PW  = 3538944;    // proj_w bf16 768*768*2  = 1179648
static constexpr size_t O_F1W = 4718592;    // fc1_w bf16  3072*768*2 = 4718592
static constexpr size_t O_F2W = 9437184;    // fc2_w bf16  768*3072*2 = 4718592
static constexpr size_t O_WKD = 14155776;   // wk f64 (transposed [768][64]) 393216
static constexpr size_t O_A   = 14548992;   // h16 (8192*768*2) -> later xa
static constexpr size_t O_B   = 27131904;   // Q (12.58MB) -> x1 part1 -> x2
static constexpr size_t O_C   = 39714816;   // K            -> x1 part2 -> ln2q
static constexpr size_t O_D   = 52297728;   // V            -> xm
static constexpr size_t O_E   = 64880640;   // mn64 8192*64*8 = 4194304
static constexpr size_t O_G   = 69074944;   // gq bf16 4096*3072*2 = 25165824
static constexpr size_t O_IDX = 94240768;   // nidx 16384
static constexpr size_t O_SZ  = 94257152;   // szf 16384
// total = 94273536 (~89.9 MB)

// ---------------- prep: weights->bf16, wkT[c][d] = mean_h(W_k)[d][c] f64 ----------------
__global__ __launch_bounds__(256) void k_prep(
    const float* __restrict__ qkvw, const float* __restrict__ projw,
    const float* __restrict__ fc1w, const float* __restrict__ fc2w,
    u16* __restrict__ qw, u16* __restrict__ pw, u16* __restrict__ f1,
    u16* __restrict__ f2, double* __restrict__ wkT) {
  int i = blockIdx.x * 256 + threadIdx.x;
  if (i < 1769472) qw[i] = f2bf(qkvw[i]);
  else if (i < 2359296) pw[i - 1769472] = f2bf(projw[i - 1769472]);
  else if (i < 4718592) f1[i - 2359296] = f2bf(fc1w[i - 2359296]);
  else if (i < 7077888) f2[i - 4718592] = f2bf(fc2w[i - 4718592]);
  else if (i < 7127040) {
    int k = i - 7077888; int c = k >> 6, d = k & 63;
    double s = 0.0;
    #pragma unroll
    for (int h = 0; h < 12; ++h) s += (double)qkvw[(size_t)(768 + h * 64 + d) * 768 + c];
    wkT[(size_t)c * 64 + d] = s * (1.0 / 12.0);
  }
}

// ---------------- LN1 -> bf16 ----------------
__global__ __launch_bounds__(256) void k_ln1(
    const float* __restrict__ x, const float* __restrict__ g,
    const float* __restrict__ bt, u16* __restrict__ h16) {
  __shared__ float red[4];
  int row = blockIdx.x, t = threadIdx.x;
  const float* xr = x + (size_t)row * 768;
  float v0 = xr[t], v1 = xr[t + 256], v2 = xr[t + 512];
  float s = v0 + v1 + v2;
  #pragma unroll
  for (int m = 32; m >= 1; m >>= 1) s += __shfl_xor(s, m);
  if ((t & 63) == 0) red[t >> 6] = s;
  __syncthreads();
  float mu = (red[0] + red[1] + red[2] + red[3]) * (1.f / 768.f);
  float d0 = v0 - mu, d1 = v1 - mu, d2 = v2 - mu;
  float q = d0 * d0 + d1 * d1 + d2 * d2;
  #pragma unroll
  for (int m = 32; m >= 1; m >>= 1) q += __shfl_xor(q, m);
  __syncthreads();
  if ((t & 63) == 0) red[t >> 6] = q;
  __syncthreads();
  float var = (red[0] + red[1] + red[2] + red[3]) * (1.f / 768.f);
  float inv = rsqrtf(var + 1e-5f);
  u16* hq = h16 + (size_t)row * 768;
  hq[t]       = f2bf(d0 * inv * g[t] + bt[t]);
  hq[t + 256] = f2bf(d1 * inv * g[t + 256] + bt[t + 256]);
  hq[t + 512] = f2bf(d2 * inv * g[t + 512] + bt[t + 512]);
}

// ---------------- metric in f64: mn[row][d] = normalize(LN64(x) . wkT) ----------------
__global__ __launch_bounds__(256) void k_metric64(
    const float* __restrict__ x, const float* __restrict__ g,
    const float* __restrict__ bt, const double* __restrict__ wkT,
    double* __restrict__ mn) {
  __shared__ double hs[768];
  __shared__ double redd[4];
  __shared__ double part[4][64];
  int row = blockIdx.x, t = threadIdx.x;
  const float* xr = x + (size_t)row * 768;
  double v0 = xr[t], v1 = xr[t + 256], v2 = xr[t + 512];
  double s = v0 + v1 + v2;
  #pragma unroll
  for (int m = 32; m >= 1; m >>= 1) s += __shfl_xor(s, m);
  if ((t & 63) == 0) redd[t >> 6] = s;
  __syncthreads();
  double mu = (redd[0] + redd[1] + redd[2] + redd[3]) * (1.0 / 768.0);
  double d0 = v0 - mu, d1 = v1 - mu, d2 = v2 - mu;
  double q = d0 * d0 + d1 * d1 + d2 * d2;
  #pragma unroll
  for (int m = 32; m >= 1; m >>= 1) q += __shfl_xor(q, m);
  __syncthreads();
  if ((t & 63) == 0) redd[t >> 6] = q;
  __syncthreads();
  double var = (redd[0] + redd[1] + redd[2] + redd[3]) * (1.0 / 768.0);
  double inv = 1.0 / sqrt(var + 1e-5);
  hs[t]       = d0 * inv * (double)g[t] + (double)bt[t];
  hs[t + 256] = d1 * inv * (double)g[t + 256] + (double)bt[t + 256];
  hs[t + 512] = d2 * inv * (double)g[t + 512] + (double)bt[t + 512];
  __syncthreads();
  int d = t & 63, pr = t >> 6;
  double acc = 0.0;
  const double* hp = hs + pr * 192;
  const double* wp = wkT + (size_t)(pr * 192) * 64 + d;
  for (int c = 0; c < 192; ++c) acc += hp[c] * wp[(size_t)c * 64];
  part[pr][d] = acc;
  __syncthreads();
  if (t < 64) {
    double m = part[0][t] + part[1][t] + part[2][t] + part[3][t];
    double ss = m * m;
    #pragma unroll
    for (int msk = 32; msk >= 1; msk >>= 1) ss += __shfl_xor(ss, msk);
    mn[(size_t)row * 64 + t] = m / sqrt(ss);
  }
}

// ---------------- ToMe argmax (f64), one block per (b,i) ----------------
__global__ __launch_bounds__(64) void k_scores(
    const double* __restrict__ mn, int* __restrict__ nidx) {
  __shared__ double as_[64];
  int b = blockIdx.x >> 9, i = blockIdx.x & 511;
  int t = threadIdx.x;
  as_[t] = mn[((size_t)b * 1024 + 2 * i) * 64 + t];
  __syncthreads();
  double bv = -1e300; int bj = 0;
  for (int q = 0; q < 8; ++q) {
    int j = q * 64 + t;
    const double* br = mn + ((size_t)b * 1024 + 2 * j + 1) * 64;
    double a0 = 0.0, a1 = 0.0, a2 = 0.0, a3 = 0.0;
    #pragma unroll
    for (int c = 0; c < 64; c += 4) {
      a0 += as_[c]     * br[c];
      a1 += as_[c + 1] * br[c + 1];
      a2 += as_[c + 2] * br[c + 2];
      a3 += as_[c + 3] * br[c + 3];
    }
    double dv = (a0 + a1) + (a2 + a3);
    if (dv > bv || (dv == bv && j < bj)) { bv = dv; bj = j; }
  }
  #pragma unroll
  for (int m = 32; m >= 1; m >>= 1) {
    double ov = __shfl_xor(bv, m);
    int oj = __shfl_xor(bj, m);
    if (ov > bv || (ov == bv && oj < bj)) { bv = ov; bj = oj; }
  }
  if (t == 0) nidx[b * 512 + i] = bj;
}

// ---------------- bf16 MFMA GEMM, 128x128 tile, BK=64, padded-LDS reg staging ----------
// C[M,N] = A[M,K] @ B[N,K]^T ; EPI: 0=qkv scatter, 1=proj(+bias+resid->f32),
// 2=fc1(+bias,gelu->bf16), 3=fc2(+bias+resid->f32 d_out)
template <int EPI>
__global__ __launch_bounds__(256) void k_gemm(
    const u16* __restrict__ A, const u16* __restrict__ Bw,
    int M, int N, int K,
    const float* __restrict__ bias, const float* __restrict__ resid,
    u16* __restrict__ o0, u16* __restrict__ o1, u16* __restrict__ o2,
    float* __restrict__ of) {
  __shared__ u16 As[128 * 72];
  __shared__ u16 Bs[128 * 72];
  const int tid = threadIdx.x, lane = tid & 63, wid = tid >> 6;
  const int bm = blockIdx.x, bn = blockIdx.y;
  const int wm = wid >> 1, wn = wid & 1;
  vfloat4 acc[4][4];
  #pragma unroll
  for (int i = 0; i < 4; ++i)
    #pragma unroll
    for (int j = 0; j < 4; ++j) acc[i][j] = (vfloat4){0.f, 0.f, 0.f, 0.f};

  for (int kt = 0; kt < K; kt += 64) {
    vshort8 ra[4], rb[4];
    #pragma unroll
    for (int q = 0; q < 4; ++q) {
      int idx = q * 256 + tid; int r = idx >> 3, ck = idx & 7;
      ra[q] = *(const vshort8*)&A[(size_t)(bm * 128 + r) * K + kt + ck * 8];
      rb[q] = *(const vshort8*)&Bw[(size_t)(bn * 128 + r) * K + kt + ck * 8];
    }
    __syncthreads();
    #pragma unroll
    for (int q = 0; q < 4; ++q) {
      int idx = q * 256 + tid; int r = idx >> 3, ck = idx & 7;
      *(vshort8*)&As[r * 72 + ck * 8] = ra[q];
      *(vshort8*)&Bs[r * 72 + ck * 8] = rb[q];
    }
    __syncthreads();
    #pragma unroll
    for (int kc = 0; kc < 2; ++kc) {
      vshort8 av[4], bv[4];
      #pragma unroll
      for (int i = 0; i < 4; ++i) {
        int ra_ = wm * 64 + i * 16 + (lane & 15);
        av[i] = *(const vshort8*)&As[ra_ * 72 + (kc * 4 + (lane >> 4)) * 8];
      }
      #pragma unroll
      for (int i = 0; i < 4; ++i) {
        int rb_ = wn * 64 + i * 16 + (lane & 15);
        bv[i] = *(const vshort8*)&Bs[rb_ * 72 + (kc * 4 + (lane >> 4)) * 8];
      }
      #pragma unroll
      for (int mi = 0; mi < 4; ++mi)
        #pragma unroll
        for (int ni = 0; ni < 4; ++ni)
          acc[mi][ni] = __builtin_amdgcn_mfma_f32_16x16x32_bf16(av[mi], bv[ni], acc[mi][ni], 0, 0, 0);
    }
    __syncthreads();
  }

  const int rq = lane >> 4;
  #pragma unroll
  for (int mi = 0; mi < 4; ++mi) {
    #pragma unroll
    for (int ni = 0; ni < 4; ++ni) {
      #pragma unroll
      for (int r = 0; r < 4; ++r) {
        int row = bm * 128 + wm * 64 + mi * 16 + rq * 4 + r;
        int col = bn * 128 + wn * 64 + ni * 16 + (lane & 15);
        float v = acc[mi][ni][r];
        if constexpr (EPI == 0) {
          int mat = col / 768, rem = col % 768;
          int head = rem >> 6, d = rem & 63;
          int b = row >> 10, tok = row & 1023;
          u16* dst = (mat == 0) ? o0 : ((mat == 1) ? o1 : o2);
          dst[(((size_t)b * 12 + head) * 1024 + tok) * 64 + d] = f2bf(v);
        } else if constexpr (EPI == 1) {
          v += bias[col] + resid[(size_t)row * N + col];
          of[(size_t)row * N + col] = v;
        } else if constexpr (EPI == 2) {
          v += bias[col];
          v = 0.5f * v * (1.f + erff(v * 0.70710678118654752f));   // exact GELU
          o0[(size_t)row * N + col] = f2bf(v);
        } else {
          v += bias[col] + resid[(size_t)row * N + col];
          of[(size_t)row * N + col] = v;                 // f32 final output
        }
      }
    }
  }
}

// ---------------- flash attention, padded LDS, explicit barriers ----------------
__global__ __launch_bounds__(256) void k_attn(
    const u16* __restrict__ Qb, const u16* __restrict__ Kb,
    const u16* __restrict__ Vb, const float* __restrict__ asz,
    u16* __restrict__ xa) {
  __shared__ u16 Ks[64 * 72];
  __shared__ u16 Vt[64 * 72];
  __shared__ u16 Pl[4][16 * 72];
  __shared__ float la[64];
  int blk = blockIdx.x;
  int qt = blk & 15, h = (blk >> 4) % 12, b = blk / 192;
  int t = threadIdx.x, lane = t & 63, wid = t >> 6;
  const size_t bh = (size_t)b * 12 + h;
  const u16* Qp = Qb + (bh * 1024 + qt * 64 + wid * 16 + (lane & 15)) * 64;
  vshort8 qa0 = *(const vshort8*)(Qp + (lane >> 4) * 8);
  vshort8 qa1 = *(const vshort8*)(Qp + 32 + (lane >> 4) * 8);
  vfloat4 accO[4];
  #pragma unroll
  for (int i = 0; i < 4; ++i) accO[i] = (vfloat4){0.f, 0.f, 0.f, 0.f};
  float mrow[4], lrow[4];
  #pragma unroll
  for (int r = 0; r < 4; ++r) { mrow[r] = -INFINITY; lrow[r] = 0.f; }

  for (int j0 = 0; j0 < 1024; j0 += 64) {
    vshort8 kr[2];
    #pragma unroll
    for (int q = 0; q < 2; ++q) {
      int idx = q * 256 + t; int r = idx >> 3, ck = idx & 7;
      kr[q] = *(const vshort8*)&Kb[(bh * 1024 + j0 + r) * 64 + ck * 8];
    }
    int jj = t & 63, d0 = (t >> 6) * 16;
    const u16* vp = Vb + (bh * 1024 + j0 + jj) * 64 + d0;
    vshort8 v0 = *(const vshort8*)vp;
    vshort8 v1 = *(const vshort8*)(vp + 8);
    float lv = 0.f;
    if (t < 64) lv = asz[(size_t)b * 1024 + j0 + t];
    __syncthreads();                       // prior tile's LDS reads complete
    #pragma unroll
    for (int q = 0; q < 2; ++q) {
      int idx = q * 256 + t; int r = idx >> 3, ck = idx & 7;
      *(vshort8*)&Ks[r * 72 + ck * 8] = kr[q];
    }
    #pragma unroll
    for (int e = 0; e < 8; ++e) {
      Vt[(d0 + e) * 72 + jj] = (u16)v0[e];
      Vt[(d0 + 8 + e) * 72 + jj] = (u16)v1[e];
    }
    if (t < 64) la[t] = logf(lv);
    __syncthreads();

    vfloat4 sacc[4];
    #pragma unroll
    for (int jt = 0; jt < 4; ++jt) {
      int r = jt * 16 + (lane & 15);
      vshort8 kb0 = *(const vshort8*)&Ks[r * 72 + (lane >> 4) * 8];
      vshort8 kb1 = *(const vshort8*)&Ks[r * 72 + (4 + (lane >> 4)) * 8];
      vfloat4 z = (vfloat4){0.f, 0.f, 0.f, 0.f};
      z = __builtin_amdgcn_mfma_f32_16x16x32_bf16(qa0, kb0, z, 0, 0, 0);
      z = __builtin_amdgcn_mfma_f32_16x16x32_bf16(qa1, kb1, z, 0, 0, 0);
      sacc[jt] = z;
    }
    float mnew[4], fsc[4];
    #pragma unroll
    for (int r = 0; r < 4; ++r) {
      float mt = -INFINITY;
      #pragma unroll
      for (int jt = 0; jt < 4; ++jt) {
        float sv = sacc[jt][r] * 0.125f + la[jt * 16 + (lane & 15)];
        sacc[jt][r] = sv;
        mt = fmaxf(mt, sv);
      }
      mt = fmaxf(mt, __shfl_xor(mt, 1)); mt = fmaxf(mt, __shfl_xor(mt, 2));
      mt = fmaxf(mt, __shfl_xor(mt, 4)); mt = fmaxf(mt, __shfl_xor(mt, 8));
      mnew[r] = fmaxf(mrow[r], mt);
      fsc[r] = expf(mrow[r] - mnew[r]);
      mrow[r] = mnew[r];
    }
    float psum[4] = {0.f, 0.f, 0.f, 0.f};
    #pragma unroll
    for (int jt = 0; jt < 4; ++jt) {
      #pragma unroll
      for (int r = 0; r < 4; ++r) {
        float p = expf(sacc[jt][r] - mnew[r]);
        psum[r] += p;
        int q = (lane >> 4) * 4 + r;
        int j = jt * 16 + (lane & 15);
        Pl[wid][q * 72 + j] = f2bf(p);
      }
    }
    #pragma unroll
    for (int r = 0; r < 4; ++r) {
      float sv = psum[r];
      sv += __shfl_xor(sv, 1); sv += __shfl_xor(sv, 2);
      sv += __shfl_xor(sv, 4); sv += __shfl_xor(sv, 8);
      lrow[r] = lrow[r] * fsc[r] + sv;
    }
    __syncthreads();                       // P visible before PV reads
    #pragma unroll
    for (int dt = 0; dt < 4; ++dt)
      #pragma unroll
      for (int r = 0; r < 4; ++r) accO[dt][r] *= fsc[r];
    #pragma unroll
    for (int jc = 0; jc < 2; ++jc) {
      vshort8 pa = *(const vshort8*)&Pl[wid][(lane & 15) * 72 + (jc * 4 + (lane >> 4)) * 8];
      #pragma unroll
      for (int dt = 0; dt < 4; ++dt) {
        vshort8 vb8 = *(const vshort8*)&Vt[(dt * 16 + (lane & 15)) * 72 + (jc * 4 + (lane >> 4)) * 8];
        accO[dt] = __builtin_amdgcn_mfma_f32_16x16x32_bf16(pa, vb8, accO[dt], 0, 0, 0);
      }
    }
  }
  #pragma unroll
  for (int r = 0; r < 4; ++r) {
    float invl = 1.f / lrow[r];
    int row = qt * 64 + wid * 16 + (lane >> 4) * 4 + r;
    #pragma unroll
    for (int dt = 0; dt < 4; ++dt) {
      int col = h * 64 + dt * 16 + (lane & 15);
      xa[((size_t)b * 1024 + row) * 768 + col] = f2bf(accO[dt][r] * invl);
    }
  }
}

// ---------------- merge ----------------
__global__ __launch_bounds__(256) void k_merge_init(
    const float* __restrict__ x1, const float* __restrict__ asz,
    float* __restrict__ xm, float* __restrict__ szf) {
  int row = blockIdx.x;                 // b*512 + j
  int b = row >> 9, j = row & 511;
  size_t srow = (size_t)b * 1024 + 2 * j + 1;
  float s = asz[srow];
  const float* xp = x1 + srow * 768;
  float* op = xm + (size_t)row * 768;
  for (int c4 = threadIdx.x; c4 < 192; c4 += 256) {
    vfloat4 v = *(const vfloat4*)&xp[c4 * 4];
    v *= s;
    *(vfloat4*)&op[c4 * 4] = v;
  }
  if (threadIdx.x == 0) szf[row] = s;
}

__global__ __launch_bounds__(256) void k_merge_scatter(
    const float* __restrict__ x1, const float* __restrict__ asz,
    const int* __restrict__ nidx, float* __restrict__ xm, float* __restrict__ szf) {
  int row = blockIdx.x;                 // b*512 + i
  int b = row >> 9;
  int dst = nidx[row];
  size_t srow = (size_t)b * 1024 + 2 * (row & 511);
  float s = asz[srow];
  const float* xp = x1 + srow * 768;
  float* op = xm + ((size_t)b * 512 + dst) * 768;
  for (int c = threadIdx.x; c < 768; c += 256) atomicAdd(&op[c], xp[c] * s);
  if (threadIdx.x == 0) atomicAdd(&szf[b * 512 + dst], s);
}

// ---------------- x2 = xm/size; LN2 -> bf16; size -> d_out tail (f32) ----------------
__global__ __launch_bounds__(256) void k_ln2div(
    const float* __restrict__ xm, const float* __restrict__ szf,
    const float* __restrict__ g, const float* __restrict__ bt,
    float* __restrict__ x2, u16* __restrict__ ln2q, float* __restrict__ szo) {
  __shared__ float red[4];
  int row = blockIdx.x, t = threadIdx.x;
  float inv = 1.f / szf[row];
  const float* xp = xm + (size_t)row * 768;
  float v0 = xp[t] * inv, v1 = xp[t + 256] * inv, v2 = xp[t + 512] * inv;
  float* xo = x2 + (size_t)row * 768;
  xo[t] = v0; xo[t + 256] = v1; xo[t + 512] = v2;
  float s = v0 + v1 + v2;
  #pragma unroll
  for (int m = 32; m >= 1; m >>= 1) s += __shfl_xor(s, m);
  if ((t & 63) == 0) red[t >> 6] = s;
  __syncthreads();
  float mu = (red[0] + red[1] + red[2] + red[3]) * (1.f / 768.f);
  float d0 = v0 - mu, d1 = v1 - mu, d2 = v2 - mu;
  float q = d0 * d0 + d1 * d1 + d2 * d2;
  #pragma unroll
  for (int m = 32; m >= 1; m >>= 1) q += __shfl_xor(q, m);
  __syncthreads();
  if ((t & 63) == 0) red[t >> 6] = q;
  __syncthreads();
  float var = (red[0] + red[1] + red[2] + red[3]) * (1.f / 768.f);
  float is = rsqrtf(var + 1e-5f);
  u16* lo = ln2q + (size_t)row * 768;
  lo[t]       = f2bf(d0 * is * g[t] + bt[t]);
  lo[t + 256] = f2bf(d1 * is * g[t + 256] + bt[t + 256]);
  lo[t + 512] = f2bf(d2 * is * g[t + 512] + bt[t + 512]);
  if (t == 0) szo[row] = szf[row];
}

// ---------------- launch ----------------
extern "C" void kernel_launch(void* const* d_in, const int* in_sizes, int n_in,
                              void* d_out, int out_size, void* d_ws, size_t ws_size,
                              hipStream_t stream) {
  (void)in_sizes; (void)n_in; (void)out_size; (void)ws_size;
  const float* x    = (const float*)d_in[0];
  const float* asz  = (const float*)d_in[1];
  const float* ln1w = (const float*)d_in[2];
  const float* ln1b = (const float*)d_in[3];
  const float* qkvw = (const float*)d_in[4];
  const float* projw= (const float*)d_in[5];
  const float* projb= (const float*)d_in[6];
  const float* ln2w = (const float*)d_in[7];
  const float* ln2b = (const float*)d_in[8];
  const float* fc1w = (const float*)d_in[9];
  const float* fc1b = (const float*)d_in[10];
  const float* fc2w = (const float*)d_in[11];
  const float* fc2b = (const float*)d_in[12];

  char* ws = (char*)d_ws;
  u16*    qw   = (u16*)(ws + O_QW);
  u16*    pw   = (u16*)(ws + O_PW);
  u16*    f1w_ = (u16*)(ws + O_F1W);
  u16*    f2w_ = (u16*)(ws + O_F2W);
  double* wkT  = (double*)(ws + O_WKD);
  u16*    h16  = (u16*)(ws + O_A);
  u16*    xab  = (u16*)(ws + O_A);          // reuse: h16 dead after qkv GEMM
  u16*    Qb   = (u16*)(ws + O_B);
  u16*    Kb   = (u16*)(ws + O_C);
  u16*    Vb   = (u16*)(ws + O_D);
  double* mn   = (double*)(ws + O_E);
  float*  x1   = (float*)(ws + O_B);        // reuse: Q,K dead after attn (25.2MB)
  float*  xm   = (float*)(ws + O_D);        // reuse: V dead after attn
  float*  x2   = (float*)(ws + O_B);        // reuse: x1 dead after scatter
  u16*    ln2q = (u16*)(ws + O_C);          // reuse: x1 dead after scatter
  u16*    gq   = (u16*)(ws + O_G);
  int*    nidx = (int*)(ws + O_IDX);
  float*  szf  = (float*)(ws + O_SZ);

  float* outf = (float*)d_out;              // f32 output: x then size
  float* szo  = outf + 3145728;

  k_prep<<<27841, 256, 0, stream>>>(qkvw, projw, fc1w, fc2w, qw, pw, f1w_, f2w_, wkT);
  k_ln1<<<8192, 256, 0, stream>>>(x, ln1w, ln1b, h16);
  k_metric64<<<8192, 256, 0, stream>>>(x, ln1w, ln1b, wkT, mn);
  k_scores<<<4096, 64, 0, stream>>>(mn, nidx);
  k_gemm<0><<<dim3(64, 18), 256, 0, stream>>>(h16, qw, 8192, 2304, 768,
      nullptr, nullptr, Qb, Kb, Vb, nullptr);
  k_attn<<<1536, 256, 0, stream>>>(Qb, Kb, Vb, asz, xab);
  k_gemm<1><<<dim3(64, 6), 256, 0, stream>>>(xab, pw, 8192, 768, 768,
      projb, x, nullptr, nullptr, nullptr, x1);
  k_merge_init<<<4096, 256, 0, stream>>>(x1, asz, xm, szf);
  k_merge_scatter<<<4096, 256, 0, stream>>>(x1, asz, nidx, xm, szf);
  k_ln2div<<<4096, 256, 0, stream>>>(xm, szf, ln2w, ln2b, x2, ln2q, szo);
  k_gemm<2><<<dim3(32, 24), 256, 0, stream>>>(ln2q, f1w_, 4096, 3072, 768,
      fc1b, nullptr, gq, nullptr, nullptr, nullptr);
  k_gemm<3><<<dim3(32, 6), 256, 0, stream>>>(gq, f2w_, 4096, 768, 3072,
      fc2b, x2, nullptr, nullptr, nullptr, outf);
}

// Round 7
// 634.831 us; speedup vs baseline: 1.3686x; 1.1992x over previous
//
#include <hip/hip_runtime.h>
#include <hip/hip_bf16.h>
#include <math.h>

// Round 7: round-6 passing kernel (761us) + single change: k_metric64 was
// 195us at VALUBusy 10.6% (192-deep serial f64 chain, 393KB wkT re-read by
// all 8192 blocks = 3.2GB L2 traffic). Now 4 rows/block: wave-per-row LN,
// 4 independent accumulators (ILP 4), wkT traffic /4. f64 path unchanged.

typedef unsigned short u16;
typedef __attribute__((ext_vector_type(8))) short vshort8;   // 8 x bf16
typedef __attribute__((ext_vector_type(4))) float vfloat4;

#define DEVI __device__ __forceinline__

DEVI u16 f2bf(float f) {
  union { float f; unsigned u; } x{f};
  unsigned r = x.u + 0x7fffu + ((x.u >> 16) & 1u);
  return (u16)(r >> 16);
}

// ---------------- workspace layout (bytes) ----------------
static constexpr size_t O_QW  = 0;          // qkv_w bf16  2304*768*2 = 3538944
static constexpr size_t O_PW  = 3538944;    // proj_w bf16 768*768*2  = 1179648
static constexpr size_t O_F1W = 4718592;    // fc1_w bf16  3072*768*2 = 4718592
static constexpr size_t O_F2W = 9437184;    // fc2_w bf16  768*3072*2 = 4718592
static constexpr size_t O_WKD = 14155776;   // wk f64 (transposed [768][64]) 393216
static constexpr size_t O_A   = 14548992;   // h16 (8192*768*2) -> later xa
static constexpr size_t O_B   = 27131904;   // Q (12.58MB) -> x1 part1 -> x2
static constexpr size_t O_C   = 39714816;   // K            -> x1 part2 -> ln2q
static constexpr size_t O_D   = 52297728;   // V            -> xm
static constexpr size_t O_E   = 64880640;   // mn64 8192*64*8 = 4194304
static constexpr size_t O_G   = 69074944;   // gq bf16 4096*3072*2 = 25165824
static constexpr size_t O_IDX = 94240768;   // nidx 16384
static constexpr size_t O_SZ  = 94257152;   // szf 16384
// total = 94273536 (~89.9 MB)

// ---------------- prep: weights->bf16, wkT[c][d] = mean_h(W_k)[d][c] f64 ----------------
__global__ __launch_bounds__(256) void k_prep(
    const float* __restrict__ qkvw, const float* __restrict__ projw,
    const float* __restrict__ fc1w, const float* __restrict__ fc2w,
    u16* __restrict__ qw, u16* __restrict__ pw, u16* __restrict__ f1,
    u16* __restrict__ f2, double* __restrict__ wkT) {
  int i = blockIdx.x * 256 + threadIdx.x;
  if (i < 1769472) qw[i] = f2bf(qkvw[i]);
  else if (i < 2359296) pw[i - 1769472] = f2bf(projw[i - 1769472]);
  else if (i < 4718592) f1[i - 2359296] = f2bf(fc1w[i - 2359296]);
  else if (i < 7077888) f2[i - 4718592] = f2bf(fc2w[i - 4718592]);
  else if (i < 7127040) {
    int k = i - 7077888; int c = k >> 6, d = k & 63;
    double s = 0.0;
    #pragma unroll
    for (int h = 0; h < 12; ++h) s += (double)qkvw[(size_t)(768 + h * 64 + d) * 768 + c];
    wkT[(size_t)c * 64 + d] = s * (1.0 / 12.0);
  }
}

// ---------------- LN1 -> bf16 ----------------
__global__ __launch_bounds__(256) void k_ln1(
    const float* __restrict__ x, const float* __restrict__ g,
    const float* __restrict__ bt, u16* __restrict__ h16) {
  __shared__ float red[4];
  int row = blockIdx.x, t = threadIdx.x;
  const float* xr = x + (size_t)row * 768;
  float v0 = xr[t], v1 = xr[t + 256], v2 = xr[t + 512];
  float s = v0 + v1 + v2;
  #pragma unroll
  for (int m = 32; m >= 1; m >>= 1) s += __shfl_xor(s, m);
  if ((t & 63) == 0) red[t >> 6] = s;
  __syncthreads();
  float mu = (red[0] + red[1] + red[2] + red[3]) * (1.f / 768.f);
  float d0 = v0 - mu, d1 = v1 - mu, d2 = v2 - mu;
  float q = d0 * d0 + d1 * d1 + d2 * d2;
  #pragma unroll
  for (int m = 32; m >= 1; m >>= 1) q += __shfl_xor(q, m);
  __syncthreads();
  if ((t & 63) == 0) red[t >> 6] = q;
  __syncthreads();
  float var = (red[0] + red[1] + red[2] + red[3]) * (1.f / 768.f);
  float inv = rsqrtf(var + 1e-5f);
  u16* hq = h16 + (size_t)row * 768;
  hq[t]       = f2bf(d0 * inv * g[t] + bt[t]);
  hq[t + 256] = f2bf(d1 * inv * g[t + 256] + bt[t + 256]);
  hq[t + 512] = f2bf(d2 * inv * g[t + 512] + bt[t + 512]);
}

// ---------------- metric f64, 4 rows/block: mn[row][d] = normalize(LN64(x).wkT) ------
__global__ __launch_bounds__(256) void k_metric64(
    const float* __restrict__ x, const float* __restrict__ g,
    const float* __restrict__ bt, const double* __restrict__ wkT,
    double* __restrict__ mn) {
  __shared__ double hs[4][768];       // 24.5 KB: LN'd rows in f64
  __shared__ double part[4][4][64];   // 8 KB: [c-partition][row][d]
  int t = threadIdx.x, lane = t & 63, w = t >> 6;

  // --- phase 1: LN row r0+w by wave w (64 lanes, 12 elems/lane) ---
  {
    int row = blockIdx.x * 4 + w;
    const float* xr = x + (size_t)row * 768;
    double v[12];
    double s = 0.0;
    #pragma unroll
    for (int k = 0; k < 12; ++k) { v[k] = (double)xr[lane + 64 * k]; s += v[k]; }
    #pragma unroll
    for (int m = 32; m >= 1; m >>= 1) s += __shfl_xor(s, m);
    double mu = s * (1.0 / 768.0);
    double q = 0.0;
    #pragma unroll
    for (int k = 0; k < 12; ++k) { double d = v[k] - mu; q += d * d; }
    #pragma unroll
    for (int m = 32; m >= 1; m >>= 1) q += __shfl_xor(q, m);
    double inv = 1.0 / sqrt(q * (1.0 / 768.0) + 1e-5);
    #pragma unroll
    for (int k = 0; k < 12; ++k) {
      int c = lane + 64 * k;
      hs[w][c] = (v[k] - mu) * inv * (double)g[c] + (double)bt[c];
    }
  }
  __syncthreads();

  // --- phase 2: dot. thread = (c-partition w, d=lane); 4 row-accumulators ---
  {
    double a0 = 0.0, a1 = 0.0, a2 = 0.0, a3 = 0.0;
    const double* wp = wkT + (size_t)(w * 192) * 64 + lane;
    for (int c = 0; c < 192; ++c) {
      double wv = wp[(size_t)c * 64];
      int cg = w * 192 + c;
      a0 += hs[0][cg] * wv;
      a1 += hs[1][cg] * wv;
      a2 += hs[2][cg] * wv;
      a3 += hs[3][cg] * wv;
    }
    part[w][0][lane] = a0; part[w][1][lane] = a1;
    part[w][2][lane] = a2; part[w][3][lane] = a3;
  }
  __syncthreads();

  // --- phase 3: reduce partitions; row w handled by wave w; normalize ---
  {
    double m = part[0][w][lane] + part[1][w][lane] + part[2][w][lane] + part[3][w][lane];
    double ss = m * m;
    #pragma unroll
    for (int msk = 32; msk >= 1; msk >>= 1) ss += __shfl_xor(ss, msk);
    int row = blockIdx.x * 4 + w;
    mn[(size_t)row * 64 + lane] = m / sqrt(ss);
  }
}

// ---------------- ToMe argmax (f64), one block per (b,i) ----------------
__global__ __launch_bounds__(64) void k_scores(
    const double* __restrict__ mn, int* __restrict__ nidx) {
  __shared__ double as_[64];
  int b = blockIdx.x >> 9, i = blockIdx.x & 511;
  int t = threadIdx.x;
  as_[t] = mn[((size_t)b * 1024 + 2 * i) * 64 + t];
  __syncthreads();
  double bv = -1e300; int bj = 0;
  for (int q = 0; q < 8; ++q) {
    int j = q * 64 + t;
    const double* br = mn + ((size_t)b * 1024 + 2 * j + 1) * 64;
    double a0 = 0.0, a1 = 0.0, a2 = 0.0, a3 = 0.0;
    #pragma unroll
    for (int c = 0; c < 64; c += 4) {
      a0 += as_[c]     * br[c];
      a1 += as_[c + 1] * br[c + 1];
      a2 += as_[c + 2] * br[c + 2];
      a3 += as_[c + 3] * br[c + 3];
    }
    double dv = (a0 + a1) + (a2 + a3);
    if (dv > bv || (dv == bv && j < bj)) { bv = dv; bj = j; }
  }
  #pragma unroll
  for (int m = 32; m >= 1; m >>= 1) {
    double ov = __shfl_xor(bv, m);
    int oj = __shfl_xor(bj, m);
    if (ov > bv || (ov == bv && oj < bj)) { bv = ov; bj = oj; }
  }
  if (t == 0) nidx[b * 512 + i] = bj;
}

// ---------------- bf16 MFMA GEMM, 128x128 tile, BK=64, padded-LDS reg staging ----------
// C[M,N] = A[M,K] @ B[N,K]^T ; EPI: 0=qkv scatter, 1=proj(+bias+resid->f32),
// 2=fc1(+bias,gelu->bf16), 3=fc2(+bias+resid->f32 d_out)
template <int EPI>
__global__ __launch_bounds__(256) void k_gemm(
    const u16* __restrict__ A, const u16* __restrict__ Bw,
    int M, int N, int K,
    const float* __restrict__ bias, const float* __restrict__ resid,
    u16* __restrict__ o0, u16* __restrict__ o1, u16* __restrict__ o2,
    float* __restrict__ of) {
  __shared__ u16 As[128 * 72];
  __shared__ u16 Bs[128 * 72];
  const int tid = threadIdx.x, lane = tid & 63, wid = tid >> 6;
  const int bm = blockIdx.x, bn = blockIdx.y;
  const int wm = wid >> 1, wn = wid & 1;
  vfloat4 acc[4][4];
  #pragma unroll
  for (int i = 0; i < 4; ++i)
    #pragma unroll
    for (int j = 0; j < 4; ++j) acc[i][j] = (vfloat4){0.f, 0.f, 0.f, 0.f};

  for (int kt = 0; kt < K; kt += 64) {
    vshort8 ra[4], rb[4];
    #pragma unroll
    for (int q = 0; q < 4; ++q) {
      int idx = q * 256 + tid; int r = idx >> 3, ck = idx & 7;
      ra[q] = *(const vshort8*)&A[(size_t)(bm * 128 + r) * K + kt + ck * 8];
      rb[q] = *(const vshort8*)&Bw[(size_t)(bn * 128 + r) * K + kt + ck * 8];
    }
    __syncthreads();
    #pragma unroll
    for (int q = 0; q < 4; ++q) {
      int idx = q * 256 + tid; int r = idx >> 3, ck = idx & 7;
      *(vshort8*)&As[r * 72 + ck * 8] = ra[q];
      *(vshort8*)&Bs[r * 72 + ck * 8] = rb[q];
    }
    __syncthreads();
    #pragma unroll
    for (int kc = 0; kc < 2; ++kc) {
      vshort8 av[4], bv[4];
      #pragma unroll
      for (int i = 0; i < 4; ++i) {
        int ra_ = wm * 64 + i * 16 + (lane & 15);
        av[i] = *(const vshort8*)&As[ra_ * 72 + (kc * 4 + (lane >> 4)) * 8];
      }
      #pragma unroll
      for (int i = 0; i < 4; ++i) {
        int rb_ = wn * 64 + i * 16 + (lane & 15);
        bv[i] = *(const vshort8*)&Bs[rb_ * 72 + (kc * 4 + (lane >> 4)) * 8];
      }
      #pragma unroll
      for (int mi = 0; mi < 4; ++mi)
        #pragma unroll
        for (int ni = 0; ni < 4; ++ni)
          acc[mi][ni] = __builtin_amdgcn_mfma_f32_16x16x32_bf16(av[mi], bv[ni], acc[mi][ni], 0, 0, 0);
    }
    __syncthreads();
  }

  const int rq = lane >> 4;
  #pragma unroll
  for (int mi = 0; mi < 4; ++mi) {
    #pragma unroll
    for (int ni = 0; ni < 4; ++ni) {
      #pragma unroll
      for (int r = 0; r < 4; ++r) {
        int row = bm * 128 + wm * 64 + mi * 16 + rq * 4 + r;
        int col = bn * 128 + wn * 64 + ni * 16 + (lane & 15);
        float v = acc[mi][ni][r];
        if constexpr (EPI == 0) {
          int mat = col / 768, rem = col % 768;
          int head = rem >> 6, d = rem & 63;
          int b = row >> 10, tok = row & 1023;
          u16* dst = (mat == 0) ? o0 : ((mat == 1) ? o1 : o2);
          dst[(((size_t)b * 12 + head) * 1024 + tok) * 64 + d] = f2bf(v);
        } else if constexpr (EPI == 1) {
          v += bias[col] + resid[(size_t)row * N + col];
          of[(size_t)row * N + col] = v;
        } else if constexpr (EPI == 2) {
          v += bias[col];
          v = 0.5f * v * (1.f + erff(v * 0.70710678118654752f));   // exact GELU
          o0[(size_t)row * N + col] = f2bf(v);
        } else {
          v += bias[col] + resid[(size_t)row * N + col];
          of[(size_t)row * N + col] = v;                 // f32 final output
        }
      }
    }
  }
}

// ---------------- flash attention, padded LDS, explicit barriers ----------------
__global__ __launch_bounds__(256) void k_attn(
    const u16* __restrict__ Qb, const u16* __restrict__ Kb,
    const u16* __restrict__ Vb, const float* __restrict__ asz,
    u16* __restrict__ xa) {
  __shared__ u16 Ks[64 * 72];
  __shared__ u16 Vt[64 * 72];
  __shared__ u16 Pl[4][16 * 72];
  __shared__ float la[64];
  int blk = blockIdx.x;
  int qt = blk & 15, h = (blk >> 4) % 12, b = blk / 192;
  int t = threadIdx.x, lane = t & 63, wid = t >> 6;
  const size_t bh = (size_t)b * 12 + h;
  const u16* Qp = Qb + (bh * 1024 + qt * 64 + wid * 16 + (lane & 15)) * 64;
  vshort8 qa0 = *(const vshort8*)(Qp + (lane >> 4) * 8);
  vshort8 qa1 = *(const vshort8*)(Qp + 32 + (lane >> 4) * 8);
  vfloat4 accO[4];
  #pragma unroll
  for (int i = 0; i < 4; ++i) accO[i] = (vfloat4){0.f, 0.f, 0.f, 0.f};
  float mrow[4], lrow[4];
  #pragma unroll
  for (int r = 0; r < 4; ++r) { mrow[r] = -INFINITY; lrow[r] = 0.f; }

  for (int j0 = 0; j0 < 1024; j0 += 64) {
    vshort8 kr[2];
    #pragma unroll
    for (int q = 0; q < 2; ++q) {
      int idx = q * 256 + t; int r = idx >> 3, ck = idx & 7;
      kr[q] = *(const vshort8*)&Kb[(bh * 1024 + j0 + r) * 64 + ck * 8];
    }
    int jj = t & 63, d0 = (t >> 6) * 16;
    const u16* vp = Vb + (bh * 1024 + j0 + jj) * 64 + d0;
    vshort8 v0 = *(const vshort8*)vp;
    vshort8 v1 = *(const vshort8*)(vp + 8);
    float lv = 0.f;
    if (t < 64) lv = asz[(size_t)b * 1024 + j0 + t];
    __syncthreads();                       // prior tile's LDS reads complete
    #pragma unroll
    for (int q = 0; q < 2; ++q) {
      int idx = q * 256 + t; int r = idx >> 3, ck = idx & 7;
      *(vshort8*)&Ks[r * 72 + ck * 8] = kr[q];
    }
    #pragma unroll
    for (int e = 0; e < 8; ++e) {
      Vt[(d0 + e) * 72 + jj] = (u16)v0[e];
      Vt[(d0 + 8 + e) * 72 + jj] = (u16)v1[e];
    }
    if (t < 64) la[t] = logf(lv);
    __syncthreads();

    vfloat4 sacc[4];
    #pragma unroll
    for (int jt = 0; jt < 4; ++jt) {
      int r = jt * 16 + (lane & 15);
      vshort8 kb0 = *(const vshort8*)&Ks[r * 72 + (lane >> 4) * 8];
      vshort8 kb1 = *(const vshort8*)&Ks[r * 72 + (4 + (lane >> 4)) * 8];
      vfloat4 z = (vfloat4){0.f, 0.f, 0.f, 0.f};
      z = __builtin_amdgcn_mfma_f32_16x16x32_bf16(qa0, kb0, z, 0, 0, 0);
      z = __builtin_amdgcn_mfma_f32_16x16x32_bf16(qa1, kb1, z, 0, 0, 0);
      sacc[jt] = z;
    }
    float mnew[4], fsc[4];
    #pragma unroll
    for (int r = 0; r < 4; ++r) {
      float mt = -INFINITY;
      #pragma unroll
      for (int jt = 0; jt < 4; ++jt) {
        float sv = sacc[jt][r] * 0.125f + la[jt * 16 + (lane & 15)];
        sacc[jt][r] = sv;
        mt = fmaxf(mt, sv);
      }
      mt = fmaxf(mt, __shfl_xor(mt, 1)); mt = fmaxf(mt, __shfl_xor(mt, 2));
      mt = fmaxf(mt, __shfl_xor(mt, 4)); mt = fmaxf(mt, __shfl_xor(mt, 8));
      mnew[r] = fmaxf(mrow[r], mt);
      fsc[r] = expf(mrow[r] - mnew[r]);
      mrow[r] = mnew[r];
    }
    float psum[4] = {0.f, 0.f, 0.f, 0.f};
    #pragma unroll
    for (int jt = 0; jt < 4; ++jt) {
      #pragma unroll
      for (int r = 0; r < 4; ++r) {
        float p = expf(sacc[jt][r] - mnew[r]);
        psum[r] += p;
        int q = (lane >> 4) * 4 + r;
        int j = jt * 16 + (lane & 15);
        Pl[wid][q * 72 + j] = f2bf(p);
      }
    }
    #pragma unroll
    for (int r = 0; r < 4; ++r) {
      float sv = psum[r];
      sv += __shfl_xor(sv, 1); sv += __shfl_xor(sv, 2);
      sv += __shfl_xor(sv, 4); sv += __shfl_xor(sv, 8);
      lrow[r] = lrow[r] * fsc[r] + sv;
    }
    __syncthreads();                       // P visible before PV reads
    #pragma unroll
    for (int dt = 0; dt < 4; ++dt)
      #pragma unroll
      for (int r = 0; r < 4; ++r) accO[dt][r] *= fsc[r];
    #pragma unroll
    for (int jc = 0; jc < 2; ++jc) {
      vshort8 pa = *(const vshort8*)&Pl[wid][(lane & 15) * 72 + (jc * 4 + (lane >> 4)) * 8];
      #pragma unroll
      for (int dt = 0; dt < 4; ++dt) {
        vshort8 vb8 = *(const vshort8*)&Vt[(dt * 16 + (lane & 15)) * 72 + (jc * 4 + (lane >> 4)) * 8];
        accO[dt] = __builtin_amdgcn_mfma_f32_16x16x32_bf16(pa, vb8, accO[dt], 0, 0, 0);
      }
    }
  }
  #pragma unroll
  for (int r = 0; r < 4; ++r) {
    float invl = 1.f / lrow[r];
    int row = qt * 64 + wid * 16 + (lane >> 4) * 4 + r;
    #pragma unroll
    for (int dt = 0; dt < 4; ++dt) {
      int col = h * 64 + dt * 16 + (lane & 15);
      xa[((size_t)b * 1024 + row) * 768 + col] = f2bf(accO[dt][r] * invl);
    }
  }
}

// ---------------- merge ----------------
__global__ __launch_bounds__(256) void k_merge_init(
    const float* __restrict__ x1, const float* __restrict__ asz,
    float* __restrict__ xm, float* __restrict__ szf) {
  int row = blockIdx.x;                 // b*512 + j
  int b = row >> 9, j = row & 511;
  size_t srow = (size_t)b * 1024 + 2 * j + 1;
  float s = asz[srow];
  const float* xp = x1 + srow * 768;
  float* op = xm + (size_t)row * 768;
  for (int c4 = threadIdx.x; c4 < 192; c4 += 256) {
    vfloat4 v = *(const vfloat4*)&xp[c4 * 4];
    v *= s;
    *(vfloat4*)&op[c4 * 4] = v;
  }
  if (threadIdx.x == 0) szf[row] = s;
}

__global__ __launch_bounds__(256) void k_merge_scatter(
    const float* __restrict__ x1, const float* __restrict__ asz,
    const int* __restrict__ nidx, float* __restrict__ xm, float* __restrict__ szf) {
  int row = blockIdx.x;                 // b*512 + i
  int b = row >> 9;
  int dst = nidx[row];
  size_t srow = (size_t)b * 1024 + 2 * (row & 511);
  float s = asz[srow];
  const float* xp = x1 + srow * 768;
  float* op = xm + ((size_t)b * 512 + dst) * 768;
  for (int c = threadIdx.x; c < 768; c += 256) atomicAdd(&op[c], xp[c] * s);
  if (threadIdx.x == 0) atomicAdd(&szf[b * 512 + dst], s);
}

// ---------------- x2 = xm/size; LN2 -> bf16; size -> d_out tail (f32) ----------------
__global__ __launch_bounds__(256) void k_ln2div(
    const float* __restrict__ xm, const float* __restrict__ szf,
    const float* __restrict__ g, const float* __restrict__ bt,
    float* __restrict__ x2, u16* __restrict__ ln2q, float* __restrict__ szo) {
  __shared__ float red[4];
  int row = blockIdx.x, t = threadIdx.x;
  float inv = 1.f / szf[row];
  const float* xp = xm + (size_t)row * 768;
  float v0 = xp[t] * inv, v1 = xp[t + 256] * inv, v2 = xp[t + 512] * inv;
  float* xo = x2 + (size_t)row * 768;
  xo[t] = v0; xo[t + 256] = v1; xo[t + 512] = v2;
  float s = v0 + v1 + v2;
  #pragma unroll
  for (int m = 32; m >= 1; m >>= 1) s += __shfl_xor(s, m);
  if ((t & 63) == 0) red[t >> 6] = s;
  __syncthreads();
  float mu = (red[0] + red[1] + red[2] + red[3]) * (1.f / 768.f);
  float d0 = v0 - mu, d1 = v1 - mu, d2 = v2 - mu;
  float q = d0 * d0 + d1 * d1 + d2 * d2;
  #pragma unroll
  for (int m = 32; m >= 1; m >>= 1) q += __shfl_xor(q, m);
  __syncthreads();
  if ((t & 63) == 0) red[t >> 6] = q;
  __syncthreads();
  float var = (red[0] + red[1] + red[2] + red[3]) * (1.f / 768.f);
  float is = rsqrtf(var + 1e-5f);
  u16* lo = ln2q + (size_t)row * 768;
  lo[t]       = f2bf(d0 * is * g[t] + bt[t]);
  lo[t + 256] = f2bf(d1 * is * g[t + 256] + bt[t + 256]);
  lo[t + 512] = f2bf(d2 * is * g[t + 512] + bt[t + 512]);
  if (t == 0) szo[row] = szf[row];
}

// ---------------- launch ----------------
extern "C" void kernel_launch(void* const* d_in, const int* in_sizes, int n_in,
                              void* d_out, int out_size, void* d_ws, size_t ws_size,
                              hipStream_t stream) {
  (void)in_sizes; (void)n_in; (void)out_size; (void)ws_size;
  const float* x    = (const float*)d_in[0];
  const float* asz  = (const float*)d_in[1];
  const float* ln1w = (const float*)d_in[2];
  const float* ln1b = (const float*)d_in[3];
  const float* qkvw = (const float*)d_in[4];
  const float* projw= (const float*)d_in[5];
  const float* projb= (const float*)d_in[6];
  const float* ln2w = (const float*)d_in[7];
  const float* ln2b = (const float*)d_in[8];
  const float* fc1w = (const float*)d_in[9];
  const float* fc1b = (const float*)d_in[10];
  const float* fc2w = (const float*)d_in[11];
  const float* fc2b = (const float*)d_in[12];

  char* ws = (char*)d_ws;
  u16*    qw   = (u16*)(ws + O_QW);
  u16*    pw   = (u16*)(ws + O_PW);
  u16*    f1w_ = (u16*)(ws + O_F1W);
  u16*    f2w_ = (u16*)(ws + O_F2W);
  double* wkT  = (double*)(ws + O_WKD);
  u16*    h16  = (u16*)(ws + O_A);
  u16*    xab  = (u16*)(ws + O_A);          // reuse: h16 dead after qkv GEMM
  u16*    Qb   = (u16*)(ws + O_B);
  u16*    Kb   = (u16*)(ws + O_C);
  u16*    Vb   = (u16*)(ws + O_D);
  double* mn   = (double*)(ws + O_E);
  float*  x1   = (float*)(ws + O_B);        // reuse: Q,K dead after attn (25.2MB)
  float*  xm   = (float*)(ws + O_D);        // reuse: V dead after attn
  float*  x2   = (float*)(ws + O_B);        // reuse: x1 dead after scatter
  u16*    ln2q = (u16*)(ws + O_C);          // reuse: x1 dead after scatter
  u16*    gq   = (u16*)(ws + O_G);
  int*    nidx = (int*)(ws + O_IDX);
  float*  szf  = (float*)(ws + O_SZ);

  float* outf = (float*)d_out;              // f32 output: x then size
  float* szo  = outf + 3145728;

  k_prep<<<27841, 256, 0, stream>>>(qkvw, projw, fc1w, fc2w, qw, pw, f1w_, f2w_, wkT);
  k_ln1<<<8192, 256, 0, stream>>>(x, ln1w, ln1b, h16);
  k_metric64<<<2048, 256, 0, stream>>>(x, ln1w, ln1b, wkT, mn);
  k_scores<<<4096, 64, 0, stream>>>(mn, nidx);
  k_gemm<0><<<dim3(64, 18), 256, 0, stream>>>(h16, qw, 8192, 2304, 768,
      nullptr, nullptr, Qb, Kb, Vb, nullptr);
  k_attn<<<1536, 256, 0, stream>>>(Qb, Kb, Vb, asz, xab);
  k_gemm<1><<<dim3(64, 6), 256, 0, stream>>>(xab, pw, 8192, 768, 768,
      projb, x, nullptr, nullptr, nullptr, x1);
  k_merge_init<<<4096, 256, 0, stream>>>(x1, asz, xm, szf);
  k_merge_scatter<<<4096, 256, 0, stream>>>(x1, asz, nidx, xm, szf);
  k_ln2div<<<4096, 256, 0, stream>>>(xm, szf, ln2w, ln2b, x2, ln2q, szo);
  k_gemm<2><<<dim3(32, 24), 256, 0, stream>>>(ln2q, f1w_, 4096, 3072, 768,
      fc1b, nullptr, gq, nullptr, nullptr, nullptr);
  k_gemm<3><<<dim3(32, 6), 256, 0, stream>>>(gq, f2w_, 4096, 768, 3072,
      fc2b, x2, nullptr, nullptr, nullptr, outf);
}

// Round 9
// 508.167 us; speedup vs baseline: 1.7097x; 1.2493x over previous
//
#include <hip/hip_runtime.h>
#include <hip/hip_bf16.h>
#include <math.h>

// Round 9 = Round 8 resubmitted (GPU acquisition timeout; never ran).
// Round-7 passing kernel (635us) + single change: k_scores (146us, VALU 3%,
// 1GB L2 re-read) -> tiled f64 score-GEMM with fused per-tile argmax
// (512 blocks, 64x64 tiles in LDS, 4x4 microkernel) + tiny jtile-reduce kernel.
// First-max tie-break preserved exactly (ascending j scan + (v==bv && j<bj)).

typedef unsigned short u16;
typedef __attribute__((ext_vector_type(8))) short vshort8;   // 8 x bf16
typedef __attribute__((ext_vector_type(4))) float vfloat4;

#define DEVI __device__ __forceinline__

DEVI u16 f2bf(float f) {
  union { float f; unsigned u; } x{f};
  unsigned r = x.u + 0x7fffu + ((x.u >> 16) & 1u);
  return (u16)(r >> 16);
}

// ---------------- workspace layout (bytes) ----------------
static constexpr size_t O_QW  = 0;          // qkv_w bf16  2304*768*2 = 3538944
static constexpr size_t O_PW  = 3538944;    // proj_w bf16 768*768*2  = 1179648
static constexpr size_t O_F1W = 4718592;    // fc1_w bf16  3072*768*2 = 4718592
static constexpr size_t O_F2W = 9437184;    // fc2_w bf16  768*3072*2 = 4718592
static constexpr size_t O_WKD = 14155776;   // wk f64 (transposed [768][64]) 393216
static constexpr size_t O_A   = 14548992;   // h16 (8192*768*2) -> later xa
static constexpr size_t O_B   = 27131904;   // Q (12.58MB) -> x1 part1 -> x2
static constexpr size_t O_C   = 39714816;   // K            -> x1 part2 -> ln2q
static constexpr size_t O_D   = 52297728;   // V            -> xm
static constexpr size_t O_E   = 64880640;   // mn64 8192*64*8 = 4194304
static constexpr size_t O_G   = 69074944;   // gq bf16 4096*3072*2 = 25165824
static constexpr size_t O_IDX = 94240768;   // nidx 16384
static constexpr size_t O_SZ  = 94257152;   // szf 16384
static constexpr size_t O_PART= 94273536;   // score partials 8*512*8*16 = 524288
// total = 94797824 (~90.4 MB)

// ---------------- prep: weights->bf16, wkT[c][d] = mean_h(W_k)[d][c] f64 ----------------
__global__ __launch_bounds__(256) void k_prep(
    const float* __restrict__ qkvw, const float* __restrict__ projw,
    const float* __restrict__ fc1w, const float* __restrict__ fc2w,
    u16* __restrict__ qw, u16* __restrict__ pw, u16* __restrict__ f1,
    u16* __restrict__ f2, double* __restrict__ wkT) {
  int i = blockIdx.x * 256 + threadIdx.x;
  if (i < 1769472) qw[i] = f2bf(qkvw[i]);
  else if (i < 2359296) pw[i - 1769472] = f2bf(projw[i - 1769472]);
  else if (i < 4718592) f1[i - 2359296] = f2bf(fc1w[i - 2359296]);
  else if (i < 7077888) f2[i - 4718592] = f2bf(fc2w[i - 4718592]);
  else if (i < 7127040) {
    int k = i - 7077888; int c = k >> 6, d = k & 63;
    double s = 0.0;
    #pragma unroll
    for (int h = 0; h < 12; ++h) s += (double)qkvw[(size_t)(768 + h * 64 + d) * 768 + c];
    wkT[(size_t)c * 64 + d] = s * (1.0 / 12.0);
  }
}

// ---------------- LN1 -> bf16 ----------------
__global__ __launch_bounds__(256) void k_ln1(
    const float* __restrict__ x, const float* __restrict__ g,
    const float* __restrict__ bt, u16* __restrict__ h16) {
  __shared__ float red[4];
  int row = blockIdx.x, t = threadIdx.x;
  const float* xr = x + (size_t)row * 768;
  float v0 = xr[t], v1 = xr[t + 256], v2 = xr[t + 512];
  float s = v0 + v1 + v2;
  #pragma unroll
  for (int m = 32; m >= 1; m >>= 1) s += __shfl_xor(s, m);
  if ((t & 63) == 0) red[t >> 6] = s;
  __syncthreads();
  float mu = (red[0] + red[1] + red[2] + red[3]) * (1.f / 768.f);
  float d0 = v0 - mu, d1 = v1 - mu, d2 = v2 - mu;
  float q = d0 * d0 + d1 * d1 + d2 * d2;
  #pragma unroll
  for (int m = 32; m >= 1; m >>= 1) q += __shfl_xor(q, m);
  __syncthreads();
  if ((t & 63) == 0) red[t >> 6] = q;
  __syncthreads();
  float var = (red[0] + red[1] + red[2] + red[3]) * (1.f / 768.f);
  float inv = rsqrtf(var + 1e-5f);
  u16* hq = h16 + (size_t)row * 768;
  hq[t]       = f2bf(d0 * inv * g[t] + bt[t]);
  hq[t + 256] = f2bf(d1 * inv * g[t + 256] + bt[t + 256]);
  hq[t + 512] = f2bf(d2 * inv * g[t + 512] + bt[t + 512]);
}

// ---------------- metric f64, 4 rows/block: mn[row][d] = normalize(LN64(x).wkT) ------
__global__ __launch_bounds__(256) void k_metric64(
    const float* __restrict__ x, const float* __restrict__ g,
    const float* __restrict__ bt, const double* __restrict__ wkT,
    double* __restrict__ mn) {
  __shared__ double hs[4][768];       // 24.5 KB: LN'd rows in f64
  __shared__ double part[4][4][64];   // 8 KB: [c-partition][row][d]
  int t = threadIdx.x, lane = t & 63, w = t >> 6;

  {
    int row = blockIdx.x * 4 + w;
    const float* xr = x + (size_t)row * 768;
    double v[12];
    double s = 0.0;
    #pragma unroll
    for (int k = 0; k < 12; ++k) { v[k] = (double)xr[lane + 64 * k]; s += v[k]; }
    #pragma unroll
    for (int m = 32; m >= 1; m >>= 1) s += __shfl_xor(s, m);
    double mu = s * (1.0 / 768.0);
    double q = 0.0;
    #pragma unroll
    for (int k = 0; k < 12; ++k) { double d = v[k] - mu; q += d * d; }
    #pragma unroll
    for (int m = 32; m >= 1; m >>= 1) q += __shfl_xor(q, m);
    double inv = 1.0 / sqrt(q * (1.0 / 768.0) + 1e-5);
    #pragma unroll
    for (int k = 0; k < 12; ++k) {
      int c = lane + 64 * k;
      hs[w][c] = (v[k] - mu) * inv * (double)g[c] + (double)bt[c];
    }
  }
  __syncthreads();

  {
    double a0 = 0.0, a1 = 0.0, a2 = 0.0, a3 = 0.0;
    const double* wp = wkT + (size_t)(w * 192) * 64 + lane;
    for (int c = 0; c < 192; ++c) {
      double wv = wp[(size_t)c * 64];
      int cg = w * 192 + c;
      a0 += hs[0][cg] * wv;
      a1 += hs[1][cg] * wv;
      a2 += hs[2][cg] * wv;
      a3 += hs[3][cg] * wv;
    }
    part[w][0][lane] = a0; part[w][1][lane] = a1;
    part[w][2][lane] = a2; part[w][3][lane] = a3;
  }
  __syncthreads();

  {
    double m = part[0][w][lane] + part[1][w][lane] + part[2][w][lane] + part[3][w][lane];
    double ss = m * m;
    #pragma unroll
    for (int msk = 32; msk >= 1; msk >>= 1) ss += __shfl_xor(ss, msk);
    int row = blockIdx.x * 4 + w;
    mn[(size_t)row * 64 + lane] = m / sqrt(ss);
  }
}

// ---------------- ToMe scores: tiled f64 GEMM + fused per-tile argmax ----------------
// block = (b, itile, jtile); 64x64 tile; partial[b][i][jt] = (maxval, jglobal)
__global__ __launch_bounds__(256) void k_scores_tile(
    const double* __restrict__ mn, double2* __restrict__ part) {
  __shared__ double as_[64][66];
  __shared__ double bs_[64][66];
  int blk = blockIdx.x;
  int b = blk >> 6, it = (blk >> 3) & 7, jt = blk & 7;
  int t = threadIdx.x, tx = t & 15, ty = t >> 4;
  #pragma unroll
  for (int l = 0; l < 16; ++l) {
    int idx = l * 256 + t;
    int r = idx >> 6, c = idx & 63;
    as_[r][c] = mn[((size_t)b * 1024 + 2 * (it * 64 + r)) * 64 + c];
    bs_[r][c] = mn[((size_t)b * 1024 + 2 * (jt * 64 + r) + 1) * 64 + c];
  }
  __syncthreads();
  double acc[4][4];
  #pragma unroll
  for (int mi = 0; mi < 4; ++mi)
    #pragma unroll
    for (int nj = 0; nj < 4; ++nj) acc[mi][nj] = 0.0;
  for (int c = 0; c < 64; ++c) {
    double av[4], bv[4];
    #pragma unroll
    for (int mi = 0; mi < 4; ++mi) av[mi] = as_[ty + 16 * mi][c];
    #pragma unroll
    for (int nj = 0; nj < 4; ++nj) bv[nj] = bs_[tx + 16 * nj][c];
    #pragma unroll
    for (int mi = 0; mi < 4; ++mi)
      #pragma unroll
      for (int nj = 0; nj < 4; ++nj) acc[mi][nj] += av[mi] * bv[nj];
  }
  // per-i argmax over the 64 j's of this tile (ascending j, first-max ties)
  #pragma unroll
  for (int mi = 0; mi < 4; ++mi) {
    double bv_ = acc[mi][0]; int bj_ = tx;
    #pragma unroll
    for (int nj = 1; nj < 4; ++nj) {
      int j = tx + 16 * nj;
      if (acc[mi][nj] > bv_ || (acc[mi][nj] == bv_ && j < bj_)) { bv_ = acc[mi][nj]; bj_ = j; }
    }
    #pragma unroll
    for (int m = 1; m <= 8; m <<= 1) {
      double ov = __shfl_xor(bv_, m);
      int oj = __shfl_xor(bj_, m);
      if (ov > bv_ || (ov == bv_ && oj < bj_)) { bv_ = ov; bj_ = oj; }
    }
    if (tx == 0) {
      int i = it * 64 + ty + 16 * mi;
      part[((size_t)b * 512 + i) * 8 + jt] = make_double2(bv_, (double)(jt * 64 + bj_));
    }
  }
}

__global__ __launch_bounds__(256) void k_scores_red(
    const double2* __restrict__ part, int* __restrict__ nidx) {
  int id = blockIdx.x * 256 + threadIdx.x;      // b*512 + i
  const double2* p = part + (size_t)id * 8;
  double bv = p[0].x; int bj = (int)p[0].y;
  #pragma unroll
  for (int k = 1; k < 8; ++k) {
    double v = p[k].x; int j = (int)p[k].y;
    if (v > bv || (v == bv && j < bj)) { bv = v; bj = j; }
  }
  nidx[id] = bj;
}

// ---------------- bf16 MFMA GEMM, 128x128 tile, BK=64, padded-LDS reg staging ----------
// C[M,N] = A[M,K] @ B[N,K]^T ; EPI: 0=qkv scatter, 1=proj(+bias+resid->f32),
// 2=fc1(+bias,gelu->bf16), 3=fc2(+bias+resid->f32 d_out)
template <int EPI>
__global__ __launch_bounds__(256) void k_gemm(
    const u16* __restrict__ A, const u16* __restrict__ Bw,
    int M, int N, int K,
    const float* __restrict__ bias, const float* __restrict__ resid,
    u16* __restrict__ o0, u16* __restrict__ o1, u16* __restrict__ o2,
    float* __restrict__ of) {
  __shared__ u16 As[128 * 72];
  __shared__ u16 Bs[128 * 72];
  const int tid = threadIdx.x, lane = tid & 63, wid = tid >> 6;
  const int bm = blockIdx.x, bn = blockIdx.y;
  const int wm = wid >> 1, wn = wid & 1;
  vfloat4 acc[4][4];
  #pragma unroll
  for (int i = 0; i < 4; ++i)
    #pragma unroll
    for (int j = 0; j < 4; ++j) acc[i][j] = (vfloat4){0.f, 0.f, 0.f, 0.f};

  for (int kt = 0; kt < K; kt += 64) {
    vshort8 ra[4], rb[4];
    #pragma unroll
    for (int q = 0; q < 4; ++q) {
      int idx = q * 256 + tid; int r = idx >> 3, ck = idx & 7;
      ra[q] = *(const vshort8*)&A[(size_t)(bm * 128 + r) * K + kt + ck * 8];
      rb[q] = *(const vshort8*)&Bw[(size_t)(bn * 128 + r) * K + kt + ck * 8];
    }
    __syncthreads();
    #pragma unroll
    for (int q = 0; q < 4; ++q) {
      int idx = q * 256 + tid; int r = idx >> 3, ck = idx & 7;
      *(vshort8*)&As[r * 72 + ck * 8] = ra[q];
      *(vshort8*)&Bs[r * 72 + ck * 8] = rb[q];
    }
    __syncthreads();
    #pragma unroll
    for (int kc = 0; kc < 2; ++kc) {
      vshort8 av[4], bv[4];
      #pragma unroll
      for (int i = 0; i < 4; ++i) {
        int ra_ = wm * 64 + i * 16 + (lane & 15);
        av[i] = *(const vshort8*)&As[ra_ * 72 + (kc * 4 + (lane >> 4)) * 8];
      }
      #pragma unroll
      for (int i = 0; i < 4; ++i) {
        int rb_ = wn * 64 + i * 16 + (lane & 15);
        bv[i] = *(const vshort8*)&Bs[rb_ * 72 + (kc * 4 + (lane >> 4)) * 8];
      }
      #pragma unroll
      for (int mi = 0; mi < 4; ++mi)
        #pragma unroll
        for (int ni = 0; ni < 4; ++ni)
          acc[mi][ni] = __builtin_amdgcn_mfma_f32_16x16x32_bf16(av[mi], bv[ni], acc[mi][ni], 0, 0, 0);
    }
    __syncthreads();
  }

  const int rq = lane >> 4;
  #pragma unroll
  for (int mi = 0; mi < 4; ++mi) {
    #pragma unroll
    for (int ni = 0; ni < 4; ++ni) {
      #pragma unroll
      for (int r = 0; r < 4; ++r) {
        int row = bm * 128 + wm * 64 + mi * 16 + rq * 4 + r;
        int col = bn * 128 + wn * 64 + ni * 16 + (lane & 15);
        float v = acc[mi][ni][r];
        if constexpr (EPI == 0) {
          int mat = col / 768, rem = col % 768;
          int head = rem >> 6, d = rem & 63;
          int b = row >> 10, tok = row & 1023;
          u16* dst = (mat == 0) ? o0 : ((mat == 1) ? o1 : o2);
          dst[(((size_t)b * 12 + head) * 1024 + tok) * 64 + d] = f2bf(v);
        } else if constexpr (EPI == 1) {
          v += bias[col] + resid[(size_t)row * N + col];
          of[(size_t)row * N + col] = v;
        } else if constexpr (EPI == 2) {
          v += bias[col];
          v = 0.5f * v * (1.f + erff(v * 0.70710678118654752f));   // exact GELU
          o0[(size_t)row * N + col] = f2bf(v);
        } else {
          v += bias[col] + resid[(size_t)row * N + col];
          of[(size_t)row * N + col] = v;                 // f32 final output
        }
      }
    }
  }
}

// ---------------- flash attention, padded LDS, explicit barriers ----------------
__global__ __launch_bounds__(256) void k_attn(
    const u16* __restrict__ Qb, const u16* __restrict__ Kb,
    const u16* __restrict__ Vb, const float* __restrict__ asz,
    u16* __restrict__ xa) {
  __shared__ u16 Ks[64 * 72];
  __shared__ u16 Vt[64 * 72];
  __shared__ u16 Pl[4][16 * 72];
  __shared__ float la[64];
  int blk = blockIdx.x;
  int qt = blk & 15, h = (blk >> 4) % 12, b = blk / 192;
  int t = threadIdx.x, lane = t & 63, wid = t >> 6;
  const size_t bh = (size_t)b * 12 + h;
  const u16* Qp = Qb + (bh * 1024 + qt * 64 + wid * 16 + (lane & 15)) * 64;
  vshort8 qa0 = *(const vshort8*)(Qp + (lane >> 4) * 8);
  vshort8 qa1 = *(const vshort8*)(Qp + 32 + (lane >> 4) * 8);
  vfloat4 accO[4];
  #pragma unroll
  for (int i = 0; i < 4; ++i) accO[i] = (vfloat4){0.f, 0.f, 0.f, 0.f};
  float mrow[4], lrow[4];
  #pragma unroll
  for (int r = 0; r < 4; ++r) { mrow[r] = -INFINITY; lrow[r] = 0.f; }

  for (int j0 = 0; j0 < 1024; j0 += 64) {
    vshort8 kr[2];
    #pragma unroll
    for (int q = 0; q < 2; ++q) {
      int idx = q * 256 + t; int r = idx >> 3, ck = idx & 7;
      kr[q] = *(const vshort8*)&Kb[(bh * 1024 + j0 + r) * 64 + ck * 8];
    }
    int jj = t & 63, d0 = (t >> 6) * 16;
    const u16* vp = Vb + (bh * 1024 + j0 + jj) * 64 + d0;
    vshort8 v0 = *(const vshort8*)vp;
    vshort8 v1 = *(const vshort8*)(vp + 8);
    float lv = 0.f;
    if (t < 64) lv = asz[(size_t)b * 1024 + j0 + t];
    __syncthreads();                       // prior tile's LDS reads complete
    #pragma unroll
    for (int q = 0; q < 2; ++q) {
      int idx = q * 256 + t; int r = idx >> 3, ck = idx & 7;
      *(vshort8*)&Ks[r * 72 + ck * 8] = kr[q];
    }
    #pragma unroll
    for (int e = 0; e < 8; ++e) {
      Vt[(d0 + e) * 72 + jj] = (u16)v0[e];
      Vt[(d0 + 8 + e) * 72 + jj] = (u16)v1[e];
    }
    if (t < 64) la[t] = logf(lv);
    __syncthreads();

    vfloat4 sacc[4];
    #pragma unroll
    for (int jt = 0; jt < 4; ++jt) {
      int r = jt * 16 + (lane & 15);
      vshort8 kb0 = *(const vshort8*)&Ks[r * 72 + (lane >> 4) * 8];
      vshort8 kb1 = *(const vshort8*)&Ks[r * 72 + (4 + (lane >> 4)) * 8];
      vfloat4 z = (vfloat4){0.f, 0.f, 0.f, 0.f};
      z = __builtin_amdgcn_mfma_f32_16x16x32_bf16(qa0, kb0, z, 0, 0, 0);
      z = __builtin_amdgcn_mfma_f32_16x16x32_bf16(qa1, kb1, z, 0, 0, 0);
      sacc[jt] = z;
    }
    float mnew[4], fsc[4];
    #pragma unroll
    for (int r = 0; r < 4; ++r) {
      float mt = -INFINITY;
      #pragma unroll
      for (int jt = 0; jt < 4; ++jt) {
        float sv = sacc[jt][r] * 0.125f + la[jt * 16 + (lane & 15)];
        sacc[jt][r] = sv;
        mt = fmaxf(mt, sv);
      }
      mt = fmaxf(mt, __shfl_xor(mt, 1)); mt = fmaxf(mt, __shfl_xor(mt, 2));
      mt = fmaxf(mt, __shfl_xor(mt, 4)); mt = fmaxf(mt, __shfl_xor(mt, 8));
      mnew[r] = fmaxf(mrow[r], mt);
      fsc[r] = expf(mrow[r] - mnew[r]);
      mrow[r] = mnew[r];
    }
    float psum[4] = {0.f, 0.f, 0.f, 0.f};
    #pragma unroll
    for (int jt = 0; jt < 4; ++jt) {
      #pragma unroll
      for (int r = 0; r < 4; ++r) {
        float p = expf(sacc[jt][r] - mnew[r]);
        psum[r] += p;
        int q = (lane >> 4) * 4 + r;
        int j = jt * 16 + (lane & 15);
        Pl[wid][q * 72 + j] = f2bf(p);
      }
    }
    #pragma unroll
    for (int r = 0; r < 4; ++r) {
      float sv = psum[r];
      sv += __shfl_xor(sv, 1); sv += __shfl_xor(sv, 2);
      sv += __shfl_xor(sv, 4); sv += __shfl_xor(sv, 8);
      lrow[r] = lrow[r] * fsc[r] + sv;
    }
    __syncthreads();                       // P visible before PV reads
    #pragma unroll
    for (int dt = 0; dt < 4; ++dt)
      #pragma unroll
      for (int r = 0; r < 4; ++r) accO[dt][r] *= fsc[r];
    #pragma unroll
    for (int jc = 0; jc < 2; ++jc) {
      vshort8 pa = *(const vshort8*)&Pl[wid][(lane & 15) * 72 + (jc * 4 + (lane >> 4)) * 8];
      #pragma unroll
      for (int dt = 0; dt < 4; ++dt) {
        vshort8 vb8 = *(const vshort8*)&Vt[(dt * 16 + (lane & 15)) * 72 + (jc * 4 + (lane >> 4)) * 8];
        accO[dt] = __builtin_amdgcn_mfma_f32_16x16x32_bf16(pa, vb8, accO[dt], 0, 0, 0);
      }
    }
  }
  #pragma unroll
  for (int r = 0; r < 4; ++r) {
    float invl = 1.f / lrow[r];
    int row = qt * 64 + wid * 16 + (lane >> 4) * 4 + r;
    #pragma unroll
    for (int dt = 0; dt < 4; ++dt) {
      int col = h * 64 + dt * 16 + (lane & 15);
      xa[((size_t)b * 1024 + row) * 768 + col] = f2bf(accO[dt][r] * invl);
    }
  }
}

// ---------------- merge ----------------
__global__ __launch_bounds__(256) void k_merge_init(
    const float* __restrict__ x1, const float* __restrict__ asz,
    float* __restrict__ xm, float* __restrict__ szf) {
  int row = blockIdx.x;                 // b*512 + j
  int b = row >> 9, j = row & 511;
  size_t srow = (size_t)b * 1024 + 2 * j + 1;
  float s = asz[srow];
  const float* xp = x1 + srow * 768;
  float* op = xm + (size_t)row * 768;
  for (int c4 = threadIdx.x; c4 < 192; c4 += 256) {
    vfloat4 v = *(const vfloat4*)&xp[c4 * 4];
    v *= s;
    *(vfloat4*)&op[c4 * 4] = v;
  }
  if (threadIdx.x == 0) szf[row] = s;
}

__global__ __launch_bounds__(256) void k_merge_scatter(
    const float* __restrict__ x1, const float* __restrict__ asz,
    const int* __restrict__ nidx, float* __restrict__ xm, float* __restrict__ szf) {
  int row = blockIdx.x;                 // b*512 + i
  int b = row >> 9;
  int dst = nidx[row];
  size_t srow = (size_t)b * 1024 + 2 * (row & 511);
  float s = asz[srow];
  const float* xp = x1 + srow * 768;
  float* op = xm + ((size_t)b * 512 + dst) * 768;
  for (int c = threadIdx.x; c < 768; c += 256) atomicAdd(&op[c], xp[c] * s);
  if (threadIdx.x == 0) atomicAdd(&szf[b * 512 + dst], s);
}

// ---------------- x2 = xm/size; LN2 -> bf16; size -> d_out tail (f32) ----------------
__global__ __launch_bounds__(256) void k_ln2div(
    const float* __restrict__ xm, const float* __restrict__ szf,
    const float* __restrict__ g, const float* __restrict__ bt,
    float* __restrict__ x2, u16* __restrict__ ln2q, float* __restrict__ szo) {
  __shared__ float red[4];
  int row = blockIdx.x, t = threadIdx.x;
  float inv = 1.f / szf[row];
  const float* xp = xm + (size_t)row * 768;
  float v0 = xp[t] * inv, v1 = xp[t + 256] * inv, v2 = xp[t + 512] * inv;
  float* xo = x2 + (size_t)row * 768;
  xo[t] = v0; xo[t + 256] = v1; xo[t + 512] = v2;
  float s = v0 + v1 + v2;
  #pragma unroll
  for (int m = 32; m >= 1; m >>= 1) s += __shfl_xor(s, m);
  if ((t & 63) == 0) red[t >> 6] = s;
  __syncthreads();
  float mu = (red[0] + red[1] + red[2] + red[3]) * (1.f / 768.f);
  float d0 = v0 - mu, d1 = v1 - mu, d2 = v2 - mu;
  float q = d0 * d0 + d1 * d1 + d2 * d2;
  #pragma unroll
  for (int m = 32; m >= 1; m >>= 1) q += __shfl_xor(q, m);
  __syncthreads();
  if ((t & 63) == 0) red[t >> 6] = q;
  __syncthreads();
  float var = (red[0] + red[1] + red[2] + red[3]) * (1.f / 768.f);
  float is = rsqrtf(var + 1e-5f);
  u16* lo = ln2q + (size_t)row * 768;
  lo[t]       = f2bf(d0 * is * g[t] + bt[t]);
  lo[t + 256] = f2bf(d1 * is * g[t + 256] + bt[t + 256]);
  lo[t + 512] = f2bf(d2 * is * g[t + 512] + bt[t + 512]);
  if (t == 0) szo[row] = szf[row];
}

// ---------------- launch ----------------
extern "C" void kernel_launch(void* const* d_in, const int* in_sizes, int n_in,
                              void* d_out, int out_size, void* d_ws, size_t ws_size,
                              hipStream_t stream) {
  (void)in_sizes; (void)n_in; (void)out_size; (void)ws_size;
  const float* x    = (const float*)d_in[0];
  const float* asz  = (const float*)d_in[1];
  const float* ln1w = (const float*)d_in[2];
  const float* ln1b = (const float*)d_in[3];
  const float* qkvw = (const float*)d_in[4];
  const float* projw= (const float*)d_in[5];
  const float* projb= (const float*)d_in[6];
  const float* ln2w = (const float*)d_in[7];
  const float* ln2b = (const float*)d_in[8];
  const float* fc1w = (const float*)d_in[9];
  const float* fc1b = (const float*)d_in[10];
  const float* fc2w = (const float*)d_in[11];
  const float* fc2b = (const float*)d_in[12];

  char* ws = (char*)d_ws;
  u16*    qw   = (u16*)(ws + O_QW);
  u16*    pw   = (u16*)(ws + O_PW);
  u16*    f1w_ = (u16*)(ws + O_F1W);
  u16*    f2w_ = (u16*)(ws + O_F2W);
  double* wkT  = (double*)(ws + O_WKD);
  u16*    h16  = (u16*)(ws + O_A);
  u16*    xab  = (u16*)(ws + O_A);          // reuse: h16 dead after qkv GEMM
  u16*    Qb   = (u16*)(ws + O_B);
  u16*    Kb   = (u16*)(ws + O_C);
  u16*    Vb   = (u16*)(ws + O_D);
  double* mn   = (double*)(ws + O_E);
  float*  x1   = (float*)(ws + O_B);        // reuse: Q,K dead after attn (25.2MB)
  float*  xm   = (float*)(ws + O_D);        // reuse: V dead after attn
  float*  x2   = (float*)(ws + O_B);        // reuse: x1 dead after scatter
  u16*    ln2q = (u16*)(ws + O_C);          // reuse: x1 dead after scatter
  u16*    gq   = (u16*)(ws + O_G);
  int*    nidx = (int*)(ws + O_IDX);
  float*  szf  = (float*)(ws + O_SZ);
  double2* spart = (double2*)(ws + O_PART);

  float* outf = (float*)d_out;              // f32 output: x then size
  float* szo  = outf + 3145728;

  k_prep<<<27841, 256, 0, stream>>>(qkvw, projw, fc1w, fc2w, qw, pw, f1w_, f2w_, wkT);
  k_ln1<<<8192, 256, 0, stream>>>(x, ln1w, ln1b, h16);
  k_metric64<<<2048, 256, 0, stream>>>(x, ln1w, ln1b, wkT, mn);
  k_scores_tile<<<512, 256, 0, stream>>>(mn, spart);
  k_scores_red<<<16, 256, 0, stream>>>(spart, nidx);
  k_gemm<0><<<dim3(64, 18), 256, 0, stream>>>(h16, qw, 8192, 2304, 768,
      nullptr, nullptr, Qb, Kb, Vb, nullptr);
  k_attn<<<1536, 256, 0, stream>>>(Qb, Kb, Vb, asz, xab);
  k_gemm<1><<<dim3(64, 6), 256, 0, stream>>>(xab, pw, 8192, 768, 768,
      projb, x, nullptr, nullptr, nullptr, x1);
  k_merge_init<<<4096, 256, 0, stream>>>(x1, asz, xm, szf);
  k_merge_scatter<<<4096, 256, 0, stream>>>(x1, asz, nidx, xm, szf);
  k_ln2div<<<4096, 256, 0, stream>>>(xm, szf, ln2w, ln2b, x2, ln2q, szo);
  k_gemm<2><<<dim3(32, 24), 256, 0, stream>>>(ln2q, f1w_, 4096, 3072, 768,
      fc1b, nullptr, gq, nullptr, nullptr, nullptr);
  k_gemm<3><<<dim3(32, 6), 256, 0, stream>>>(gq, f2w_, 4096, 768, 3072,
      fc2b, x2, nullptr, nullptr, nullptr, outf);
}

// Round 10
// 486.331 us; speedup vs baseline: 1.7865x; 1.0449x over previous
//
#include <hip/hip_runtime.h>
#include <hip/hip_bf16.h>
#include <math.h>

// Round 10: round-9 passing kernel (508us) + attention VALU fixes:
// (1) expf/logf -> __expf/__logf (libm expansion ~20 ops -> v_exp_f32, 2 ops;
//     was ~400 VALU ops/tile, VALUBusy 67%).
// (2) 0.125 scale folded into Q quantization at qkv epilogue (exact exponent
//     shift -> S bit-identical, 16 v_mul/tile removed).
// (3) V-transpose staging: 2 j's packed per u32 write (16 b16 -> 8 b32,
//     conflict-free banks). Everything else unchanged.

typedef unsigned short u16;
typedef __attribute__((ext_vector_type(8))) short vshort8;   // 8 x bf16
typedef __attribute__((ext_vector_type(4))) float vfloat4;

#define DEVI __device__ __forceinline__

DEVI u16 f2bf(float f) {
  union { float f; unsigned u; } x{f};
  unsigned r = x.u + 0x7fffu + ((x.u >> 16) & 1u);
  return (u16)(r >> 16);
}

// ---------------- workspace layout (bytes) ----------------
static constexpr size_t O_QW  = 0;          // qkv_w bf16  2304*768*2 = 3538944
static constexpr size_t O_PW  = 3538944;    // proj_w bf16 768*768*2  = 1179648
static constexpr size_t O_F1W = 4718592;    // fc1_w bf16  3072*768*2 = 4718592
static constexpr size_t O_F2W = 9437184;    // fc2_w bf16  768*3072*2 = 4718592
static constexpr size_t O_WKD = 14155776;   // wk f64 (transposed [768][64]) 393216
static constexpr size_t O_A   = 14548992;   // h16 (8192*768*2) -> later xa
static constexpr size_t O_B   = 27131904;   // Q (12.58MB) -> x1 part1 -> x2
static constexpr size_t O_C   = 39714816;   // K            -> x1 part2 -> ln2q
static constexpr size_t O_D   = 52297728;   // V            -> xm
static constexpr size_t O_E   = 64880640;   // mn64 8192*64*8 = 4194304
static constexpr size_t O_G   = 69074944;   // gq bf16 4096*3072*2 = 25165824
static constexpr size_t O_IDX = 94240768;   // nidx 16384
static constexpr size_t O_SZ  = 94257152;   // szf 16384
static constexpr size_t O_PART= 94273536;   // score partials 8*512*8*16 = 524288
// total = 94797824 (~90.4 MB)

// ---------------- prep: weights->bf16, wkT[c][d] = mean_h(W_k)[d][c] f64 ----------------
__global__ __launch_bounds__(256) void k_prep(
    const float* __restrict__ qkvw, const float* __restrict__ projw,
    const float* __restrict__ fc1w, const float* __restrict__ fc2w,
    u16* __restrict__ qw, u16* __restrict__ pw, u16* __restrict__ f1,
    u16* __restrict__ f2, double* __restrict__ wkT) {
  int i = blockIdx.x * 256 + threadIdx.x;
  if (i < 1769472) qw[i] = f2bf(qkvw[i]);
  else if (i < 2359296) pw[i - 1769472] = f2bf(projw[i - 1769472]);
  else if (i < 4718592) f1[i - 2359296] = f2bf(fc1w[i - 2359296]);
  else if (i < 7077888) f2[i - 4718592] = f2bf(fc2w[i - 4718592]);
  else if (i < 7127040) {
    int k = i - 7077888; int c = k >> 6, d = k & 63;
    double s = 0.0;
    #pragma unroll
    for (int h = 0; h < 12; ++h) s += (double)qkvw[(size_t)(768 + h * 64 + d) * 768 + c];
    wkT[(size_t)c * 64 + d] = s * (1.0 / 12.0);
  }
}

// ---------------- LN1 -> bf16 ----------------
__global__ __launch_bounds__(256) void k_ln1(
    const float* __restrict__ x, const float* __restrict__ g,
    const float* __restrict__ bt, u16* __restrict__ h16) {
  __shared__ float red[4];
  int row = blockIdx.x, t = threadIdx.x;
  const float* xr = x + (size_t)row * 768;
  float v0 = xr[t], v1 = xr[t + 256], v2 = xr[t + 512];
  float s = v0 + v1 + v2;
  #pragma unroll
  for (int m = 32; m >= 1; m >>= 1) s += __shfl_xor(s, m);
  if ((t & 63) == 0) red[t >> 6] = s;
  __syncthreads();
  float mu = (red[0] + red[1] + red[2] + red[3]) * (1.f / 768.f);
  float d0 = v0 - mu, d1 = v1 - mu, d2 = v2 - mu;
  float q = d0 * d0 + d1 * d1 + d2 * d2;
  #pragma unroll
  for (int m = 32; m >= 1; m >>= 1) q += __shfl_xor(q, m);
  __syncthreads();
  if ((t & 63) == 0) red[t >> 6] = q;
  __syncthreads();
  float var = (red[0] + red[1] + red[2] + red[3]) * (1.f / 768.f);
  float inv = rsqrtf(var + 1e-5f);
  u16* hq = h16 + (size_t)row * 768;
  hq[t]       = f2bf(d0 * inv * g[t] + bt[t]);
  hq[t + 256] = f2bf(d1 * inv * g[t + 256] + bt[t + 256]);
  hq[t + 512] = f2bf(d2 * inv * g[t + 512] + bt[t + 512]);
}

// ---------------- metric f64, 4 rows/block: mn[row][d] = normalize(LN64(x).wkT) ------
__global__ __launch_bounds__(256) void k_metric64(
    const float* __restrict__ x, const float* __restrict__ g,
    const float* __restrict__ bt, const double* __restrict__ wkT,
    double* __restrict__ mn) {
  __shared__ double hs[4][768];       // 24.5 KB: LN'd rows in f64
  __shared__ double part[4][4][64];   // 8 KB: [c-partition][row][d]
  int t = threadIdx.x, lane = t & 63, w = t >> 6;

  {
    int row = blockIdx.x * 4 + w;
    const float* xr = x + (size_t)row * 768;
    double v[12];
    double s = 0.0;
    #pragma unroll
    for (int k = 0; k < 12; ++k) { v[k] = (double)xr[lane + 64 * k]; s += v[k]; }
    #pragma unroll
    for (int m = 32; m >= 1; m >>= 1) s += __shfl_xor(s, m);
    double mu = s * (1.0 / 768.0);
    double q = 0.0;
    #pragma unroll
    for (int k = 0; k < 12; ++k) { double d = v[k] - mu; q += d * d; }
    #pragma unroll
    for (int m = 32; m >= 1; m >>= 1) q += __shfl_xor(q, m);
    double inv = 1.0 / sqrt(q * (1.0 / 768.0) + 1e-5);
    #pragma unroll
    for (int k = 0; k < 12; ++k) {
      int c = lane + 64 * k;
      hs[w][c] = (v[k] - mu) * inv * (double)g[c] + (double)bt[c];
    }
  }
  __syncthreads();

  {
    double a0 = 0.0, a1 = 0.0, a2 = 0.0, a3 = 0.0;
    const double* wp = wkT + (size_t)(w * 192) * 64 + lane;
    for (int c = 0; c < 192; ++c) {
      double wv = wp[(size_t)c * 64];
      int cg = w * 192 + c;
      a0 += hs[0][cg] * wv;
      a1 += hs[1][cg] * wv;
      a2 += hs[2][cg] * wv;
      a3 += hs[3][cg] * wv;
    }
    part[w][0][lane] = a0; part[w][1][lane] = a1;
    part[w][2][lane] = a2; part[w][3][lane] = a3;
  }
  __syncthreads();

  {
    double m = part[0][w][lane] + part[1][w][lane] + part[2][w][lane] + part[3][w][lane];
    double ss = m * m;
    #pragma unroll
    for (int msk = 32; msk >= 1; msk >>= 1) ss += __shfl_xor(ss, msk);
    int row = blockIdx.x * 4 + w;
    mn[(size_t)row * 64 + lane] = m / sqrt(ss);
  }
}

// ---------------- ToMe scores: tiled f64 GEMM + fused per-tile argmax ----------------
__global__ __launch_bounds__(256) void k_scores_tile(
    const double* __restrict__ mn, double2* __restrict__ part) {
  __shared__ double as_[64][66];
  __shared__ double bs_[64][66];
  int blk = blockIdx.x;
  int b = blk >> 6, it = (blk >> 3) & 7, jt = blk & 7;
  int t = threadIdx.x, tx = t & 15, ty = t >> 4;
  #pragma unroll
  for (int l = 0; l < 16; ++l) {
    int idx = l * 256 + t;
    int r = idx >> 6, c = idx & 63;
    as_[r][c] = mn[((size_t)b * 1024 + 2 * (it * 64 + r)) * 64 + c];
    bs_[r][c] = mn[((size_t)b * 1024 + 2 * (jt * 64 + r) + 1) * 64 + c];
  }
  __syncthreads();
  double acc[4][4];
  #pragma unroll
  for (int mi = 0; mi < 4; ++mi)
    #pragma unroll
    for (int nj = 0; nj < 4; ++nj) acc[mi][nj] = 0.0;
  for (int c = 0; c < 64; ++c) {
    double av[4], bv[4];
    #pragma unroll
    for (int mi = 0; mi < 4; ++mi) av[mi] = as_[ty + 16 * mi][c];
    #pragma unroll
    for (int nj = 0; nj < 4; ++nj) bv[nj] = bs_[tx + 16 * nj][c];
    #pragma unroll
    for (int mi = 0; mi < 4; ++mi)
      #pragma unroll
      for (int nj = 0; nj < 4; ++nj) acc[mi][nj] += av[mi] * bv[nj];
  }
  #pragma unroll
  for (int mi = 0; mi < 4; ++mi) {
    double bv_ = acc[mi][0]; int bj_ = tx;
    #pragma unroll
    for (int nj = 1; nj < 4; ++nj) {
      int j = tx + 16 * nj;
      if (acc[mi][nj] > bv_ || (acc[mi][nj] == bv_ && j < bj_)) { bv_ = acc[mi][nj]; bj_ = j; }
    }
    #pragma unroll
    for (int m = 1; m <= 8; m <<= 1) {
      double ov = __shfl_xor(bv_, m);
      int oj = __shfl_xor(bj_, m);
      if (ov > bv_ || (ov == bv_ && oj < bj_)) { bv_ = ov; bj_ = oj; }
    }
    if (tx == 0) {
      int i = it * 64 + ty + 16 * mi;
      part[((size_t)b * 512 + i) * 8 + jt] = make_double2(bv_, (double)(jt * 64 + bj_));
    }
  }
}

__global__ __launch_bounds__(256) void k_scores_red(
    const double2* __restrict__ part, int* __restrict__ nidx) {
  int id = blockIdx.x * 256 + threadIdx.x;      // b*512 + i
  const double2* p = part + (size_t)id * 8;
  double bv = p[0].x; int bj = (int)p[0].y;
  #pragma unroll
  for (int k = 1; k < 8; ++k) {
    double v = p[k].x; int j = (int)p[k].y;
    if (v > bv || (v == bv && j < bj)) { bv = v; bj = j; }
  }
  nidx[id] = bj;
}

// ---------------- bf16 MFMA GEMM, 128x128 tile, BK=64, padded-LDS reg staging ----------
// C[M,N] = A[M,K] @ B[N,K]^T ; EPI: 0=qkv scatter (Q pre-scaled 0.125),
// 1=proj(+bias+resid->f32), 2=fc1(+bias,gelu->bf16), 3=fc2(+bias+resid->f32 d_out)
template <int EPI>
__global__ __launch_bounds__(256) void k_gemm(
    const u16* __restrict__ A, const u16* __restrict__ Bw,
    int M, int N, int K,
    const float* __restrict__ bias, const float* __restrict__ resid,
    u16* __restrict__ o0, u16* __restrict__ o1, u16* __restrict__ o2,
    float* __restrict__ of) {
  __shared__ u16 As[128 * 72];
  __shared__ u16 Bs[128 * 72];
  const int tid = threadIdx.x, lane = tid & 63, wid = tid >> 6;
  const int bm = blockIdx.x, bn = blockIdx.y;
  const int wm = wid >> 1, wn = wid & 1;
  vfloat4 acc[4][4];
  #pragma unroll
  for (int i = 0; i < 4; ++i)
    #pragma unroll
    for (int j = 0; j < 4; ++j) acc[i][j] = (vfloat4){0.f, 0.f, 0.f, 0.f};

  for (int kt = 0; kt < K; kt += 64) {
    vshort8 ra[4], rb[4];
    #pragma unroll
    for (int q = 0; q < 4; ++q) {
      int idx = q * 256 + tid; int r = idx >> 3, ck = idx & 7;
      ra[q] = *(const vshort8*)&A[(size_t)(bm * 128 + r) * K + kt + ck * 8];
      rb[q] = *(const vshort8*)&Bw[(size_t)(bn * 128 + r) * K + kt + ck * 8];
    }
    __syncthreads();
    #pragma unroll
    for (int q = 0; q < 4; ++q) {
      int idx = q * 256 + tid; int r = idx >> 3, ck = idx & 7;
      *(vshort8*)&As[r * 72 + ck * 8] = ra[q];
      *(vshort8*)&Bs[r * 72 + ck * 8] = rb[q];
    }
    __syncthreads();
    #pragma unroll
    for (int kc = 0; kc < 2; ++kc) {
      vshort8 av[4], bv[4];
      #pragma unroll
      for (int i = 0; i < 4; ++i) {
        int ra_ = wm * 64 + i * 16 + (lane & 15);
        av[i] = *(const vshort8*)&As[ra_ * 72 + (kc * 4 + (lane >> 4)) * 8];
      }
      #pragma unroll
      for (int i = 0; i < 4; ++i) {
        int rb_ = wn * 64 + i * 16 + (lane & 15);
        bv[i] = *(const vshort8*)&Bs[rb_ * 72 + (kc * 4 + (lane >> 4)) * 8];
      }
      #pragma unroll
      for (int mi = 0; mi < 4; ++mi)
        #pragma unroll
        for (int ni = 0; ni < 4; ++ni)
          acc[mi][ni] = __builtin_amdgcn_mfma_f32_16x16x32_bf16(av[mi], bv[ni], acc[mi][ni], 0, 0, 0);
    }
    __syncthreads();
  }

  const int rq = lane >> 4;
  #pragma unroll
  for (int mi = 0; mi < 4; ++mi) {
    #pragma unroll
    for (int ni = 0; ni < 4; ++ni) {
      #pragma unroll
      for (int r = 0; r < 4; ++r) {
        int row = bm * 128 + wm * 64 + mi * 16 + rq * 4 + r;
        int col = bn * 128 + wn * 64 + ni * 16 + (lane & 15);
        float v = acc[mi][ni][r];
        if constexpr (EPI == 0) {
          int mat = col / 768, rem = col % 768;
          int head = rem >> 6, d = rem & 63;
          int b = row >> 10, tok = row & 1023;
          u16* dst = (mat == 0) ? o0 : ((mat == 1) ? o1 : o2);
          if (mat == 0) v *= 0.125f;     // exact exponent shift; S bit-identical
          dst[(((size_t)b * 12 + head) * 1024 + tok) * 64 + d] = f2bf(v);
        } else if constexpr (EPI == 1) {
          v += bias[col] + resid[(size_t)row * N + col];
          of[(size_t)row * N + col] = v;
        } else if constexpr (EPI == 2) {
          v += bias[col];
          v = 0.5f * v * (1.f + erff(v * 0.70710678118654752f));   // exact GELU
          o0[(size_t)row * N + col] = f2bf(v);
        } else {
          v += bias[col] + resid[(size_t)row * N + col];
          of[(size_t)row * N + col] = v;                 // f32 final output
        }
      }
    }
  }
}

// ---------------- flash attention, padded LDS, explicit barriers ----------------
__global__ __launch_bounds__(256) void k_attn(
    const u16* __restrict__ Qb, const u16* __restrict__ Kb,
    const u16* __restrict__ Vb, const float* __restrict__ asz,
    u16* __restrict__ xa) {
  __shared__ u16 Ks[64 * 72];
  __shared__ u16 Vt[64 * 72];
  __shared__ u16 Pl[4][16 * 72];
  __shared__ float la[64];
  int blk = blockIdx.x;
  int qt = blk & 15, h = (blk >> 4) % 12, b = blk / 192;
  int t = threadIdx.x, lane = t & 63, wid = t >> 6;
  const size_t bh = (size_t)b * 12 + h;
  const u16* Qp = Qb + (bh * 1024 + qt * 64 + wid * 16 + (lane & 15)) * 64;
  vshort8 qa0 = *(const vshort8*)(Qp + (lane >> 4) * 8);
  vshort8 qa1 = *(const vshort8*)(Qp + 32 + (lane >> 4) * 8);
  vfloat4 accO[4];
  #pragma unroll
  for (int i = 0; i < 4; ++i) accO[i] = (vfloat4){0.f, 0.f, 0.f, 0.f};
  float mrow[4], lrow[4];
  #pragma unroll
  for (int r = 0; r < 4; ++r) { mrow[r] = -INFINITY; lrow[r] = 0.f; }

  for (int j0 = 0; j0 < 1024; j0 += 64) {
    // --- reg-stage K (2x16B), V as 2-row pairs (for packed u32 transpose) ---
    vshort8 kr[2];
    #pragma unroll
    for (int q = 0; q < 2; ++q) {
      int idx = q * 256 + t; int r = idx >> 3, ck = idx & 7;
      kr[q] = *(const vshort8*)&Kb[(bh * 1024 + j0 + r) * 64 + ck * 8];
    }
    int jp = t & 31, dg = t >> 5;          // 32 j-pairs x 8 d-groups
    int d0 = dg * 8;
    const u16* vp0 = Vb + (bh * 1024 + j0 + 2 * jp) * 64 + d0;
    vshort8 v0 = *(const vshort8*)vp0;
    vshort8 v1 = *(const vshort8*)(vp0 + 64);
    float lv = 0.f;
    if (t < 64) lv = asz[(size_t)b * 1024 + j0 + t];
    __syncthreads();                       // prior tile's LDS reads complete
    #pragma unroll
    for (int q = 0; q < 2; ++q) {
      int idx = q * 256 + t; int r = idx >> 3, ck = idx & 7;
      *(vshort8*)&Ks[r * 72 + ck * 8] = kr[q];
    }
    {
      unsigned* Vt32 = (unsigned*)Vt;      // 72 u16 = 36 u32 per d-row
      #pragma unroll
      for (int e = 0; e < 8; ++e) {
        unsigned pk = ((unsigned)(u16)v0[e]) | (((unsigned)(u16)v1[e]) << 16);
        Vt32[(d0 + e) * 36 + jp] = pk;     // banks jp+36d mod 32: conflict-free
      }
    }
    if (t < 64) la[t] = __logf(lv);
    __syncthreads();

    // --- S = QK^T (Q pre-scaled by 0.125) + log(attn_size) ---
    vfloat4 sacc[4];
    #pragma unroll
    for (int jt = 0; jt < 4; ++jt) {
      int r = jt * 16 + (lane & 15);
      vshort8 kb0 = *(const vshort8*)&Ks[r * 72 + (lane >> 4) * 8];
      vshort8 kb1 = *(const vshort8*)&Ks[r * 72 + (4 + (lane >> 4)) * 8];
      vfloat4 z = (vfloat4){0.f, 0.f, 0.f, 0.f};
      z = __builtin_amdgcn_mfma_f32_16x16x32_bf16(qa0, kb0, z, 0, 0, 0);
      z = __builtin_amdgcn_mfma_f32_16x16x32_bf16(qa1, kb1, z, 0, 0, 0);
      sacc[jt] = z;
    }
    float mnew[4], fsc[4];
    #pragma unroll
    for (int r = 0; r < 4; ++r) {
      float mt = -INFINITY;
      #pragma unroll
      for (int jt = 0; jt < 4; ++jt) {
        float sv = sacc[jt][r] + la[jt * 16 + (lane & 15)];
        sacc[jt][r] = sv;
        mt = fmaxf(mt, sv);
      }
      mt = fmaxf(mt, __shfl_xor(mt, 1)); mt = fmaxf(mt, __shfl_xor(mt, 2));
      mt = fmaxf(mt, __shfl_xor(mt, 4)); mt = fmaxf(mt, __shfl_xor(mt, 8));
      mnew[r] = fmaxf(mrow[r], mt);
      fsc[r] = __expf(mrow[r] - mnew[r]);
      mrow[r] = mnew[r];
    }
    float psum[4] = {0.f, 0.f, 0.f, 0.f};
    #pragma unroll
    for (int jt = 0; jt < 4; ++jt) {
      #pragma unroll
      for (int r = 0; r < 4; ++r) {
        float p = __expf(sacc[jt][r] - mnew[r]);
        psum[r] += p;
        int q = (lane >> 4) * 4 + r;
        int j = jt * 16 + (lane & 15);
        Pl[wid][q * 72 + j] = f2bf(p);
      }
    }
    #pragma unroll
    for (int r = 0; r < 4; ++r) {
      float sv = psum[r];
      sv += __shfl_xor(sv, 1); sv += __shfl_xor(sv, 2);
      sv += __shfl_xor(sv, 4); sv += __shfl_xor(sv, 8);
      lrow[r] = lrow[r] * fsc[r] + sv;
    }
    __syncthreads();                       // P visible before PV reads
    #pragma unroll
    for (int dt = 0; dt < 4; ++dt)
      #pragma unroll
      for (int r = 0; r < 4; ++r) accO[dt][r] *= fsc[r];
    #pragma unroll
    for (int jc = 0; jc < 2; ++jc) {
      vshort8 pa = *(const vshort8*)&Pl[wid][(lane & 15) * 72 + (jc * 4 + (lane >> 4)) * 8];
      #pragma unroll
      for (int dt = 0; dt < 4; ++dt) {
        vshort8 vb8 = *(const vshort8*)&Vt[(dt * 16 + (lane & 15)) * 72 + (jc * 4 + (lane >> 4)) * 8];
        accO[dt] = __builtin_amdgcn_mfma_f32_16x16x32_bf16(pa, vb8, accO[dt], 0, 0, 0);
      }
    }
  }
  #pragma unroll
  for (int r = 0; r < 4; ++r) {
    float invl = 1.f / lrow[r];
    int row = qt * 64 + wid * 16 + (lane >> 4) * 4 + r;
    #pragma unroll
    for (int dt = 0; dt < 4; ++dt) {
      int col = h * 64 + dt * 16 + (lane & 15);
      xa[((size_t)b * 1024 + row) * 768 + col] = f2bf(accO[dt][r] * invl);
    }
  }
}

// ---------------- merge ----------------
__global__ __launch_bounds__(256) void k_merge_init(
    const float* __restrict__ x1, const float* __restrict__ asz,
    float* __restrict__ xm, float* __restrict__ szf) {
  int row = blockIdx.x;                 // b*512 + j
  int b = row >> 9, j = row & 511;
  size_t srow = (size_t)b * 1024 + 2 * j + 1;
  float s = asz[srow];
  const float* xp = x1 + srow * 768;
  float* op = xm + (size_t)row * 768;
  for (int c4 = threadIdx.x; c4 < 192; c4 += 256) {
    vfloat4 v = *(const vfloat4*)&xp[c4 * 4];
    v *= s;
    *(vfloat4*)&op[c4 * 4] = v;
  }
  if (threadIdx.x == 0) szf[row] = s;
}

__global__ __launch_bounds__(256) void k_merge_scatter(
    const float* __restrict__ x1, const float* __restrict__ asz,
    const int* __restrict__ nidx, float* __restrict__ xm, float* __restrict__ szf) {
  int row = blockIdx.x;                 // b*512 + i
  int b = row >> 9;
  int dst = nidx[row];
  size_t srow = (size_t)b * 1024 + 2 * (row & 511);
  float s = asz[srow];
  const float* xp = x1 + srow * 768;
  float* op = xm + ((size_t)b * 512 + dst) * 768;
  for (int c = threadIdx.x; c < 768; c += 256) atomicAdd(&op[c], xp[c] * s);
  if (threadIdx.x == 0) atomicAdd(&szf[b * 512 + dst], s);
}

// ---------------- x2 = xm/size; LN2 -> bf16; size -> d_out tail (f32) ----------------
__global__ __launch_bounds__(256) void k_ln2div(
    const float* __restrict__ xm, const float* __restrict__ szf,
    const float* __restrict__ g, const float* __restrict__ bt,
    float* __restrict__ x2, u16* __restrict__ ln2q, float* __restrict__ szo) {
  __shared__ float red[4];
  int row = blockIdx.x, t = threadIdx.x;
  float inv = 1.f / szf[row];
  const float* xp = xm + (size_t)row * 768;
  float v0 = xp[t] * inv, v1 = xp[t + 256] * inv, v2 = xp[t + 512] * inv;
  float* xo = x2 + (size_t)row * 768;
  xo[t] = v0; xo[t + 256] = v1; xo[t + 512] = v2;
  float s = v0 + v1 + v2;
  #pragma unroll
  for (int m = 32; m >= 1; m >>= 1) s += __shfl_xor(s, m);
  if ((t & 63) == 0) red[t >> 6] = s;
  __syncthreads();
  float mu = (red[0] + red[1] + red[2] + red[3]) * (1.f / 768.f);
  float d0 = v0 - mu, d1 = v1 - mu, d2 = v2 - mu;
  float q = d0 * d0 + d1 * d1 + d2 * d2;
  #pragma unroll
  for (int m = 32; m >= 1; m >>= 1) q += __shfl_xor(q, m);
  __syncthreads();
  if ((t & 63) == 0) red[t >> 6] = q;
  __syncthreads();
  float var = (red[0] + red[1] + red[2] + red[3]) * (1.f / 768.f);
  float is = rsqrtf(var + 1e-5f);
  u16* lo = ln2q + (size_t)row * 768;
  lo[t]       = f2bf(d0 * is * g[t] + bt[t]);
  lo[t + 256] = f2bf(d1 * is * g[t + 256] + bt[t + 256]);
  lo[t + 512] = f2bf(d2 * is * g[t + 512] + bt[t + 512]);
  if (t == 0) szo[row] = szf[row];
}

// ---------------- launch ----------------
extern "C" void kernel_launch(void* const* d_in, const int* in_sizes, int n_in,
                              void* d_out, int out_size, void* d_ws, size_t ws_size,
                              hipStream_t stream) {
  (void)in_sizes; (void)n_in; (void)out_size; (void)ws_size;
  const float* x    = (const float*)d_in[0];
  const float* asz  = (const float*)d_in[1];
  const float* ln1w = (const float*)d_in[2];
  const float* ln1b = (const float*)d_in[3];
  const float* qkvw = (const float*)d_in[4];
  const float* projw= (const float*)d_in[5];
  const float* projb= (const float*)d_in[6];
  const float* ln2w = (const float*)d_in[7];
  const float* ln2b = (const float*)d_in[8];
  const float* fc1w = (const float*)d_in[9];
  const float* fc1b = (const float*)d_in[10];
  const float* fc2w = (const float*)d_in[11];
  const float* fc2b = (const float*)d_in[12];

  char* ws = (char*)d_ws;
  u16*    qw   = (u16*)(ws + O_QW);
  u16*    pw   = (u16*)(ws + O_PW);
  u16*    f1w_ = (u16*)(ws + O_F1W);
  u16*    f2w_ = (u16*)(ws + O_F2W);
  double* wkT  = (double*)(ws + O_WKD);
  u16*    h16  = (u16*)(ws + O_A);
  u16*    xab  = (u16*)(ws + O_A);          // reuse: h16 dead after qkv GEMM
  u16*    Qb   = (u16*)(ws + O_B);
  u16*    Kb   = (u16*)(ws + O_C);
  u16*    Vb   = (u16*)(ws + O_D);
  double* mn   = (double*)(ws + O_E);
  float*  x1   = (float*)(ws + O_B);        // reuse: Q,K dead after attn (25.2MB)
  float*  xm   = (float*)(ws + O_D);        // reuse: V dead after attn
  float*  x2   = (float*)(ws + O_B);        // reuse: x1 dead after scatter
  u16*    ln2q = (u16*)(ws + O_C);          // reuse: x1 dead after scatter
  u16*    gq   = (u16*)(ws + O_G);
  int*    nidx = (int*)(ws + O_IDX);
  float*  szf  = (float*)(ws + O_SZ);
  double2* spart = (double2*)(ws + O_PART);

  float* outf = (float*)d_out;              // f32 output: x then size
  float* szo  = outf + 3145728;

  k_prep<<<27841, 256, 0, stream>>>(qkvw, projw, fc1w, fc2w, qw, pw, f1w_, f2w_, wkT);
  k_ln1<<<8192, 256, 0, stream>>>(x, ln1w, ln1b, h16);
  k_metric64<<<2048, 256, 0, stream>>>(x, ln1w, ln1b, wkT, mn);
  k_scores_tile<<<512, 256, 0, stream>>>(mn, spart);
  k_scores_red<<<16, 256, 0, stream>>>(spart, nidx);
  k_gemm<0><<<dim3(64, 18), 256, 0, stream>>>(h16, qw, 8192, 2304, 768,
      nullptr, nullptr, Qb, Kb, Vb, nullptr);
  k_attn<<<1536, 256, 0, stream>>>(Qb, Kb, Vb, asz, xab);
  k_gemm<1><<<dim3(64, 6), 256, 0, stream>>>(xab, pw, 8192, 768, 768,
      projb, x, nullptr, nullptr, nullptr, x1);
  k_merge_init<<<4096, 256, 0, stream>>>(x1, asz, xm, szf);
  k_merge_scatter<<<4096, 256, 0, stream>>>(x1, asz, nidx, xm, szf);
  k_ln2div<<<4096, 256, 0, stream>>>(xm, szf, ln2w, ln2b, x2, ln2q, szo);
  k_gemm<2><<<dim3(32, 24), 256, 0, stream>>>(ln2q, f1w_, 4096, 3072, 768,
      fc1b, nullptr, gq, nullptr, nullptr, nullptr);
  k_gemm<3><<<dim3(32, 6), 256, 0, stream>>>(gq, f2w_, 4096, 768, 3072,
      fc2b, x2, nullptr, nullptr, nullptr, outf);
}

// Round 11
// 465.225 us; speedup vs baseline: 1.8675x; 1.0454x over previous
//
#include <hip/hip_runtime.h>
#include <hip/hip_bf16.h>
#include <math.h>

// Round 11: round-10 passing kernel (486us) + single change: k_gemm staging
// reg-staged padded LDS -> global_load_lds width-16 (m97 pattern, +69% on the
// ladder). Rule-21-correct pairing: linear LDS dest (base+lane*16), global
// source pre-swizzled gck=ck^(r&7), ds_read uses the same XOR. Staged bytes
// identical => absmax must stay exactly 0.03125 (canary for swizzle bugs).

typedef unsigned short u16;
typedef __attribute__((ext_vector_type(8))) short vshort8;   // 8 x bf16
typedef __attribute__((ext_vector_type(4))) float vfloat4;

#define DEVI __device__ __forceinline__

DEVI u16 f2bf(float f) {
  union { float f; unsigned u; } x{f};
  unsigned r = x.u + 0x7fffu + ((x.u >> 16) & 1u);
  return (u16)(r >> 16);
}

#define GLDS(g, l) __builtin_amdgcn_global_load_lds( \
    (const __attribute__((address_space(1))) void*)(g), \
    (__attribute__((address_space(3))) void*)(l), 16, 0, 0)

// ---------------- workspace layout (bytes) ----------------
static constexpr size_t O_QW  = 0;          // qkv_w bf16  2304*768*2 = 3538944
static constexpr size_t O_PW  = 3538944;    // proj_w bf16 768*768*2  = 1179648
static constexpr size_t O_F1W = 4718592;    // fc1_w bf16  3072*768*2 = 4718592
static constexpr size_t O_F2W = 9437184;    // fc2_w bf16  768*3072*2 = 4718592
static constexpr size_t O_WKD = 14155776;   // wk f64 (transposed [768][64]) 393216
static constexpr size_t O_A   = 14548992;   // h16 (8192*768*2) -> later xa
static constexpr size_t O_B   = 27131904;   // Q (12.58MB) -> x1 part1 -> x2
static constexpr size_t O_C   = 39714816;   // K            -> x1 part2 -> ln2q
static constexpr size_t O_D   = 52297728;   // V            -> xm
static constexpr size_t O_E   = 64880640;   // mn64 8192*64*8 = 4194304
static constexpr size_t O_G   = 69074944;   // gq bf16 4096*3072*2 = 25165824
static constexpr size_t O_IDX = 94240768;   // nidx 16384
static constexpr size_t O_SZ  = 94257152;   // szf 16384
static constexpr size_t O_PART= 94273536;   // score partials 8*512*8*16 = 524288
// total = 94797824 (~90.4 MB)

// ---------------- prep: weights->bf16, wkT[c][d] = mean_h(W_k)[d][c] f64 ----------------
__global__ __launch_bounds__(256) void k_prep(
    const float* __restrict__ qkvw, const float* __restrict__ projw,
    const float* __restrict__ fc1w, const float* __restrict__ fc2w,
    u16* __restrict__ qw, u16* __restrict__ pw, u16* __restrict__ f1,
    u16* __restrict__ f2, double* __restrict__ wkT) {
  int i = blockIdx.x * 256 + threadIdx.x;
  if (i < 1769472) qw[i] = f2bf(qkvw[i]);
  else if (i < 2359296) pw[i - 1769472] = f2bf(projw[i - 1769472]);
  else if (i < 4718592) f1[i - 2359296] = f2bf(fc1w[i - 2359296]);
  else if (i < 7077888) f2[i - 4718592] = f2bf(fc2w[i - 4718592]);
  else if (i < 7127040) {
    int k = i - 7077888; int c = k >> 6, d = k & 63;
    double s = 0.0;
    #pragma unroll
    for (int h = 0; h < 12; ++h) s += (double)qkvw[(size_t)(768 + h * 64 + d) * 768 + c];
    wkT[(size_t)c * 64 + d] = s * (1.0 / 12.0);
  }
}

// ---------------- LN1 -> bf16 ----------------
__global__ __launch_bounds__(256) void k_ln1(
    const float* __restrict__ x, const float* __restrict__ g,
    const float* __restrict__ bt, u16* __restrict__ h16) {
  __shared__ float red[4];
  int row = blockIdx.x, t = threadIdx.x;
  const float* xr = x + (size_t)row * 768;
  float v0 = xr[t], v1 = xr[t + 256], v2 = xr[t + 512];
  float s = v0 + v1 + v2;
  #pragma unroll
  for (int m = 32; m >= 1; m >>= 1) s += __shfl_xor(s, m);
  if ((t & 63) == 0) red[t >> 6] = s;
  __syncthreads();
  float mu = (red[0] + red[1] + red[2] + red[3]) * (1.f / 768.f);
  float d0 = v0 - mu, d1 = v1 - mu, d2 = v2 - mu;
  float q = d0 * d0 + d1 * d1 + d2 * d2;
  #pragma unroll
  for (int m = 32; m >= 1; m >>= 1) q += __shfl_xor(q, m);
  __syncthreads();
  if ((t & 63) == 0) red[t >> 6] = q;
  __syncthreads();
  float var = (red[0] + red[1] + red[2] + red[3]) * (1.f / 768.f);
  float inv = rsqrtf(var + 1e-5f);
  u16* hq = h16 + (size_t)row * 768;
  hq[t]       = f2bf(d0 * inv * g[t] + bt[t]);
  hq[t + 256] = f2bf(d1 * inv * g[t + 256] + bt[t + 256]);
  hq[t + 512] = f2bf(d2 * inv * g[t + 512] + bt[t + 512]);
}

// ---------------- metric f64, 4 rows/block: mn[row][d] = normalize(LN64(x).wkT) ------
__global__ __launch_bounds__(256) void k_metric64(
    const float* __restrict__ x, const float* __restrict__ g,
    const float* __restrict__ bt, const double* __restrict__ wkT,
    double* __restrict__ mn) {
  __shared__ double hs[4][768];       // 24.5 KB: LN'd rows in f64
  __shared__ double part[4][4][64];   // 8 KB: [c-partition][row][d]
  int t = threadIdx.x, lane = t & 63, w = t >> 6;

  {
    int row = blockIdx.x * 4 + w;
    const float* xr = x + (size_t)row * 768;
    double v[12];
    double s = 0.0;
    #pragma unroll
    for (int k = 0; k < 12; ++k) { v[k] = (double)xr[lane + 64 * k]; s += v[k]; }
    #pragma unroll
    for (int m = 32; m >= 1; m >>= 1) s += __shfl_xor(s, m);
    double mu = s * (1.0 / 768.0);
    double q = 0.0;
    #pragma unroll
    for (int k = 0; k < 12; ++k) { double d = v[k] - mu; q += d * d; }
    #pragma unroll
    for (int m = 32; m >= 1; m >>= 1) q += __shfl_xor(q, m);
    double inv = 1.0 / sqrt(q * (1.0 / 768.0) + 1e-5);
    #pragma unroll
    for (int k = 0; k < 12; ++k) {
      int c = lane + 64 * k;
      hs[w][c] = (v[k] - mu) * inv * (double)g[c] + (double)bt[c];
    }
  }
  __syncthreads();

  {
    double a0 = 0.0, a1 = 0.0, a2 = 0.0, a3 = 0.0;
    const double* wp = wkT + (size_t)(w * 192) * 64 + lane;
    for (int c = 0; c < 192; ++c) {
      double wv = wp[(size_t)c * 64];
      int cg = w * 192 + c;
      a0 += hs[0][cg] * wv;
      a1 += hs[1][cg] * wv;
      a2 += hs[2][cg] * wv;
      a3 += hs[3][cg] * wv;
    }
    part[w][0][lane] = a0; part[w][1][lane] = a1;
    part[w][2][lane] = a2; part[w][3][lane] = a3;
  }
  __syncthreads();

  {
    double m = part[0][w][lane] + part[1][w][lane] + part[2][w][lane] + part[3][w][lane];
    double ss = m * m;
    #pragma unroll
    for (int msk = 32; msk >= 1; msk >>= 1) ss += __shfl_xor(ss, msk);
    int row = blockIdx.x * 4 + w;
    mn[(size_t)row * 64 + lane] = m / sqrt(ss);
  }
}

// ---------------- ToMe scores: tiled f64 GEMM + fused per-tile argmax ----------------
__global__ __launch_bounds__(256) void k_scores_tile(
    const double* __restrict__ mn, double2* __restrict__ part) {
  __shared__ double as_[64][66];
  __shared__ double bs_[64][66];
  int blk = blockIdx.x;
  int b = blk >> 6, it = (blk >> 3) & 7, jt = blk & 7;
  int t = threadIdx.x, tx = t & 15, ty = t >> 4;
  #pragma unroll
  for (int l = 0; l < 16; ++l) {
    int idx = l * 256 + t;
    int r = idx >> 6, c = idx & 63;
    as_[r][c] = mn[((size_t)b * 1024 + 2 * (it * 64 + r)) * 64 + c];
    bs_[r][c] = mn[((size_t)b * 1024 + 2 * (jt * 64 + r) + 1) * 64 + c];
  }
  __syncthreads();
  double acc[4][4];
  #pragma unroll
  for (int mi = 0; mi < 4; ++mi)
    #pragma unroll
    for (int nj = 0; nj < 4; ++nj) acc[mi][nj] = 0.0;
  for (int c = 0; c < 64; ++c) {
    double av[4], bv[4];
    #pragma unroll
    for (int mi = 0; mi < 4; ++mi) av[mi] = as_[ty + 16 * mi][c];
    #pragma unroll
    for (int nj = 0; nj < 4; ++nj) bv[nj] = bs_[tx + 16 * nj][c];
    #pragma unroll
    for (int mi = 0; mi < 4; ++mi)
      #pragma unroll
      for (int nj = 0; nj < 4; ++nj) acc[mi][nj] += av[mi] * bv[nj];
  }
  #pragma unroll
  for (int mi = 0; mi < 4; ++mi) {
    double bv_ = acc[mi][0]; int bj_ = tx;
    #pragma unroll
    for (int nj = 1; nj < 4; ++nj) {
      int j = tx + 16 * nj;
      if (acc[mi][nj] > bv_ || (acc[mi][nj] == bv_ && j < bj_)) { bv_ = acc[mi][nj]; bj_ = j; }
    }
    #pragma unroll
    for (int m = 1; m <= 8; m <<= 1) {
      double ov = __shfl_xor(bv_, m);
      int oj = __shfl_xor(bj_, m);
      if (ov > bv_ || (ov == bv_ && oj < bj_)) { bv_ = ov; bj_ = oj; }
    }
    if (tx == 0) {
      int i = it * 64 + ty + 16 * mi;
      part[((size_t)b * 512 + i) * 8 + jt] = make_double2(bv_, (double)(jt * 64 + bj_));
    }
  }
}

__global__ __launch_bounds__(256) void k_scores_red(
    const double2* __restrict__ part, int* __restrict__ nidx) {
  int id = blockIdx.x * 256 + threadIdx.x;      // b*512 + i
  const double2* p = part + (size_t)id * 8;
  double bv = p[0].x; int bj = (int)p[0].y;
  #pragma unroll
  for (int k = 1; k < 8; ++k) {
    double v = p[k].x; int j = (int)p[k].y;
    if (v > bv || (v == bv && j < bj)) { bv = v; bj = j; }
  }
  nidx[id] = bj;
}

// ---------------- bf16 MFMA GEMM, 128x128 tile, BK=64, global_load_lds staging -------
// Linear LDS [128][64], global source pre-swizzled gck=ck^(r&7), reads use same XOR.
// C[M,N] = A[M,K] @ B[N,K]^T ; EPI: 0=qkv scatter (Q pre-scaled 0.125),
// 1=proj(+bias+resid->f32), 2=fc1(+bias,gelu->bf16), 3=fc2(+bias+resid->f32 d_out)
template <int EPI>
__global__ __launch_bounds__(256) void k_gemm(
    const u16* __restrict__ A, const u16* __restrict__ Bw,
    int M, int N, int K,
    const float* __restrict__ bias, const float* __restrict__ resid,
    u16* __restrict__ o0, u16* __restrict__ o1, u16* __restrict__ o2,
    float* __restrict__ of) {
  __shared__ u16 As[128 * 64];
  __shared__ u16 Bs[128 * 64];
  const int tid = threadIdx.x, lane = tid & 63, wid = tid >> 6;
  const int bm = blockIdx.x, bn = blockIdx.y;
  const int wm = wid >> 1, wn = wid & 1;
  vfloat4 acc[4][4];
  #pragma unroll
  for (int i = 0; i < 4; ++i)
    #pragma unroll
    for (int j = 0; j < 4; ++j) acc[i][j] = (vfloat4){0.f, 0.f, 0.f, 0.f};

  for (int kt = 0; kt < K; kt += 64) {
    #pragma unroll
    for (int c = 0; c < 4; ++c) {
      int r = (wid * 4 + c) * 8 + (lane >> 3);   // wave-linear: LDS dest = base+lane*16
      int ck = lane & 7;
      int gck = ck ^ (r & 7);                    // inverse-swizzled global source
      GLDS(A + (size_t)(bm * 128 + r) * K + kt + gck * 8, As + r * 64 + ck * 8);
      GLDS(Bw + (size_t)(bn * 128 + r) * K + kt + gck * 8, Bs + r * 64 + ck * 8);
    }
    __syncthreads();                             // vmcnt(0) drain by compiler
    #pragma unroll
    for (int kc = 0; kc < 2; ++kc) {
      vshort8 av[4], bv[4];
      #pragma unroll
      for (int i = 0; i < 4; ++i) {
        int ra_ = wm * 64 + i * 16 + (lane & 15);
        int ckA = (kc * 4 + (lane >> 4)) ^ (ra_ & 7);
        av[i] = *(const vshort8*)&As[ra_ * 64 + ckA * 8];
      }
      #pragma unroll
      for (int i = 0; i < 4; ++i) {
        int rb_ = wn * 64 + i * 16 + (lane & 15);
        int ckB = (kc * 4 + (lane >> 4)) ^ (rb_ & 7);
        bv[i] = *(const vshort8*)&Bs[rb_ * 64 + ckB * 8];
      }
      #pragma unroll
      for (int mi = 0; mi < 4; ++mi)
        #pragma unroll
        for (int ni = 0; ni < 4; ++ni)
          acc[mi][ni] = __builtin_amdgcn_mfma_f32_16x16x32_bf16(av[mi], bv[ni], acc[mi][ni], 0, 0, 0);
    }
    __syncthreads();
  }

  const int rq = lane >> 4;
  #pragma unroll
  for (int mi = 0; mi < 4; ++mi) {
    #pragma unroll
    for (int ni = 0; ni < 4; ++ni) {
      #pragma unroll
      for (int r = 0; r < 4; ++r) {
        int row = bm * 128 + wm * 64 + mi * 16 + rq * 4 + r;
        int col = bn * 128 + wn * 64 + ni * 16 + (lane & 15);
        float v = acc[mi][ni][r];
        if constexpr (EPI == 0) {
          int mat = col / 768, rem = col % 768;
          int head = rem >> 6, d = rem & 63;
          int b = row >> 10, tok = row & 1023;
          u16* dst = (mat == 0) ? o0 : ((mat == 1) ? o1 : o2);
          if (mat == 0) v *= 0.125f;     // exact exponent shift; S bit-identical
          dst[(((size_t)b * 12 + head) * 1024 + tok) * 64 + d] = f2bf(v);
        } else if constexpr (EPI == 1) {
          v += bias[col] + resid[(size_t)row * N + col];
          of[(size_t)row * N + col] = v;
        } else if constexpr (EPI == 2) {
          v += bias[col];
          v = 0.5f * v * (1.f + erff(v * 0.70710678118654752f));   // exact GELU
          o0[(size_t)row * N + col] = f2bf(v);
        } else {
          v += bias[col] + resid[(size_t)row * N + col];
          of[(size_t)row * N + col] = v;                 // f32 final output
        }
      }
    }
  }
}

// ---------------- flash attention, padded LDS, explicit barriers ----------------
__global__ __launch_bounds__(256) void k_attn(
    const u16* __restrict__ Qb, const u16* __restrict__ Kb,
    const u16* __restrict__ Vb, const float* __restrict__ asz,
    u16* __restrict__ xa) {
  __shared__ u16 Ks[64 * 72];
  __shared__ u16 Vt[64 * 72];
  __shared__ u16 Pl[4][16 * 72];
  __shared__ float la[64];
  int blk = blockIdx.x;
  int qt = blk & 15, h = (blk >> 4) % 12, b = blk / 192;
  int t = threadIdx.x, lane = t & 63, wid = t >> 6;
  const size_t bh = (size_t)b * 12 + h;
  const u16* Qp = Qb + (bh * 1024 + qt * 64 + wid * 16 + (lane & 15)) * 64;
  vshort8 qa0 = *(const vshort8*)(Qp + (lane >> 4) * 8);
  vshort8 qa1 = *(const vshort8*)(Qp + 32 + (lane >> 4) * 8);
  vfloat4 accO[4];
  #pragma unroll
  for (int i = 0; i < 4; ++i) accO[i] = (vfloat4){0.f, 0.f, 0.f, 0.f};
  float mrow[4], lrow[4];
  #pragma unroll
  for (int r = 0; r < 4; ++r) { mrow[r] = -INFINITY; lrow[r] = 0.f; }

  for (int j0 = 0; j0 < 1024; j0 += 64) {
    vshort8 kr[2];
    #pragma unroll
    for (int q = 0; q < 2; ++q) {
      int idx = q * 256 + t; int r = idx >> 3, ck = idx & 7;
      kr[q] = *(const vshort8*)&Kb[(bh * 1024 + j0 + r) * 64 + ck * 8];
    }
    int jp = t & 31, dg = t >> 5;          // 32 j-pairs x 8 d-groups
    int d0 = dg * 8;
    const u16* vp0 = Vb + (bh * 1024 + j0 + 2 * jp) * 64 + d0;
    vshort8 v0 = *(const vshort8*)vp0;
    vshort8 v1 = *(const vshort8*)(vp0 + 64);
    float lv = 0.f;
    if (t < 64) lv = asz[(size_t)b * 1024 + j0 + t];
    __syncthreads();                       // prior tile's LDS reads complete
    #pragma unroll
    for (int q = 0; q < 2; ++q) {
      int idx = q * 256 + t; int r = idx >> 3, ck = idx & 7;
      *(vshort8*)&Ks[r * 72 + ck * 8] = kr[q];
    }
    {
      unsigned* Vt32 = (unsigned*)Vt;      // 72 u16 = 36 u32 per d-row
      #pragma unroll
      for (int e = 0; e < 8; ++e) {
        unsigned pk = ((unsigned)(u16)v0[e]) | (((unsigned)(u16)v1[e]) << 16);
        Vt32[(d0 + e) * 36 + jp] = pk;     // banks jp+36d mod 32: conflict-free
      }
    }
    if (t < 64) la[t] = __logf(lv);
    __syncthreads();

    vfloat4 sacc[4];
    #pragma unroll
    for (int jt = 0; jt < 4; ++jt) {
      int r = jt * 16 + (lane & 15);
      vshort8 kb0 = *(const vshort8*)&Ks[r * 72 + (lane >> 4) * 8];
      vshort8 kb1 = *(const vshort8*)&Ks[r * 72 + (4 + (lane >> 4)) * 8];
      vfloat4 z = (vfloat4){0.f, 0.f, 0.f, 0.f};
      z = __builtin_amdgcn_mfma_f32_16x16x32_bf16(qa0, kb0, z, 0, 0, 0);
      z = __builtin_amdgcn_mfma_f32_16x16x32_bf16(qa1, kb1, z, 0, 0, 0);
      sacc[jt] = z;
    }
    float mnew[4], fsc[4];
    #pragma unroll
    for (int r = 0; r < 4; ++r) {
      float mt = -INFINITY;
      #pragma unroll
      for (int jt = 0; jt < 4; ++jt) {
        float sv = sacc[jt][r] + la[jt * 16 + (lane & 15)];
        sacc[jt][r] = sv;
        mt = fmaxf(mt, sv);
      }
      mt = fmaxf(mt, __shfl_xor(mt, 1)); mt = fmaxf(mt, __shfl_xor(mt, 2));
      mt = fmaxf(mt, __shfl_xor(mt, 4)); mt = fmaxf(mt, __shfl_xor(mt, 8));
      mnew[r] = fmaxf(mrow[r], mt);
      fsc[r] = __expf(mrow[r] - mnew[r]);
      mrow[r] = mnew[r];
    }
    float psum[4] = {0.f, 0.f, 0.f, 0.f};
    #pragma unroll
    for (int jt = 0; jt < 4; ++jt) {
      #pragma unroll
      for (int r = 0; r < 4; ++r) {
        float p = __expf(sacc[jt][r] - mnew[r]);
        psum[r] += p;
        int q = (lane >> 4) * 4 + r;
        int j = jt * 16 + (lane & 15);
        Pl[wid][q * 72 + j] = f2bf(p);
      }
    }
    #pragma unroll
    for (int r = 0; r < 4; ++r) {
      float sv = psum[r];
      sv += __shfl_xor(sv, 1); sv += __shfl_xor(sv, 2);
      sv += __shfl_xor(sv, 4); sv += __shfl_xor(sv, 8);
      lrow[r] = lrow[r] * fsc[r] + sv;
    }
    __syncthreads();                       // P visible before PV reads
    #pragma unroll
    for (int dt = 0; dt < 4; ++dt)
      #pragma unroll
      for (int r = 0; r < 4; ++r) accO[dt][r] *= fsc[r];
    #pragma unroll
    for (int jc = 0; jc < 2; ++jc) {
      vshort8 pa = *(const vshort8*)&Pl[wid][(lane & 15) * 72 + (jc * 4 + (lane >> 4)) * 8];
      #pragma unroll
      for (int dt = 0; dt < 4; ++dt) {
        vshort8 vb8 = *(const vshort8*)&Vt[(dt * 16 + (lane & 15)) * 72 + (jc * 4 + (lane >> 4)) * 8];
        accO[dt] = __builtin_amdgcn_mfma_f32_16x16x32_bf16(pa, vb8, accO[dt], 0, 0, 0);
      }
    }
  }
  #pragma unroll
  for (int r = 0; r < 4; ++r) {
    float invl = 1.f / lrow[r];
    int row = qt * 64 + wid * 16 + (lane >> 4) * 4 + r;
    #pragma unroll
    for (int dt = 0; dt < 4; ++dt) {
      int col = h * 64 + dt * 16 + (lane & 15);
      xa[((size_t)b * 1024 + row) * 768 + col] = f2bf(accO[dt][r] * invl);
    }
  }
}

// ---------------- merge ----------------
__global__ __launch_bounds__(256) void k_merge_init(
    const float* __restrict__ x1, const float* __restrict__ asz,
    float* __restrict__ xm, float* __restrict__ szf) {
  int row = blockIdx.x;                 // b*512 + j
  int b = row >> 9, j = row & 511;
  size_t srow = (size_t)b * 1024 + 2 * j + 1;
  float s = asz[srow];
  const float* xp = x1 + srow * 768;
  float* op = xm + (size_t)row * 768;
  for (int c4 = threadIdx.x; c4 < 192; c4 += 256) {
    vfloat4 v = *(const vfloat4*)&xp[c4 * 4];
    v *= s;
    *(vfloat4*)&op[c4 * 4] = v;
  }
  if (threadIdx.x == 0) szf[row] = s;
}

__global__ __launch_bounds__(256) void k_merge_scatter(
    const float* __restrict__ x1, const float* __restrict__ asz,
    const int* __restrict__ nidx, float* __restrict__ xm, float* __restrict__ szf) {
  int row = blockIdx.x;                 // b*512 + i
  int b = row >> 9;
  int dst = nidx[row];
  size_t srow = (size_t)b * 1024 + 2 * (row & 511);
  float s = asz[srow];
  const float* xp = x1 + srow * 768;
  float* op = xm + ((size_t)b * 512 + dst) * 768;
  for (int c = threadIdx.x; c < 768; c += 256) atomicAdd(&op[c], xp[c] * s);
  if (threadIdx.x == 0) atomicAdd(&szf[b * 512 + dst], s);
}

// ---------------- x2 = xm/size; LN2 -> bf16; size -> d_out tail (f32) ----------------
__global__ __launch_bounds__(256) void k_ln2div(
    const float* __restrict__ xm, const float* __restrict__ szf,
    const float* __restrict__ g, const float* __restrict__ bt,
    float* __restrict__ x2, u16* __restrict__ ln2q, float* __restrict__ szo) {
  __shared__ float red[4];
  int row = blockIdx.x, t = threadIdx.x;
  float inv = 1.f / szf[row];
  const float* xp = xm + (size_t)row * 768;
  float v0 = xp[t] * inv, v1 = xp[t + 256] * inv, v2 = xp[t + 512] * inv;
  float* xo = x2 + (size_t)row * 768;
  xo[t] = v0; xo[t + 256] = v1; xo[t + 512] = v2;
  float s = v0 + v1 + v2;
  #pragma unroll
  for (int m = 32; m >= 1; m >>= 1) s += __shfl_xor(s, m);
  if ((t & 63) == 0) red[t >> 6] = s;
  __syncthreads();
  float mu = (red[0] + red[1] + red[2] + red[3]) * (1.f / 768.f);
  float d0 = v0 - mu, d1 = v1 - mu, d2 = v2 - mu;
  float q = d0 * d0 + d1 * d1 + d2 * d2;
  #pragma unroll
  for (int m = 32; m >= 1; m >>= 1) q += __shfl_xor(q, m);
  __syncthreads();
  if ((t & 63) == 0) red[t >> 6] = q;
  __syncthreads();
  float var = (red[0] + red[1] + red[2] + red[3]) * (1.f / 768.f);
  float is = rsqrtf(var + 1e-5f);
  u16* lo = ln2q + (size_t)row * 768;
  lo[t]       = f2bf(d0 * is * g[t] + bt[t]);
  lo[t + 256] = f2bf(d1 * is * g[t + 256] + bt[t + 256]);
  lo[t + 512] = f2bf(d2 * is * g[t + 512] + bt[t + 512]);
  if (t == 0) szo[row] = szf[row];
}

// ---------------- launch ----------------
extern "C" void kernel_launch(void* const* d_in, const int* in_sizes, int n_in,
                              void* d_out, int out_size, void* d_ws, size_t ws_size,
                              hipStream_t stream) {
  (void)in_sizes; (void)n_in; (void)out_size; (void)ws_size;
  const float* x    = (const float*)d_in[0];
  const float* asz  = (const float*)d_in[1];
  const float* ln1w = (const float*)d_in[2];
  const float* ln1b = (const float*)d_in[3];
  const float* qkvw = (const float*)d_in[4];
  const float* projw= (const float*)d_in[5];
  const float* projb= (const float*)d_in[6];
  const float* ln2w = (const float*)d_in[7];
  const float* ln2b = (const float*)d_in[8];
  const float* fc1w = (const float*)d_in[9];
  const float* fc1b = (const float*)d_in[10];
  const float* fc2w = (const float*)d_in[11];
  const float* fc2b = (const float*)d_in[12];

  char* ws = (char*)d_ws;
  u16*    qw   = (u16*)(ws + O_QW);
  u16*    pw   = (u16*)(ws + O_PW);
  u16*    f1w_ = (u16*)(ws + O_F1W);
  u16*    f2w_ = (u16*)(ws + O_F2W);
  double* wkT  = (double*)(ws + O_WKD);
  u16*    h16  = (u16*)(ws + O_A);
  u16*    xab  = (u16*)(ws + O_A);          // reuse: h16 dead after qkv GEMM
  u16*    Qb   = (u16*)(ws + O_B);
  u16*    Kb   = (u16*)(ws + O_C);
  u16*    Vb   = (u16*)(ws + O_D);
  double* mn   = (double*)(ws + O_E);
  float*  x1   = (float*)(ws + O_B);        // reuse: Q,K dead after attn (25.2MB)
  float*  xm   = (float*)(ws + O_D);        // reuse: V dead after attn
  float*  x2   = (float*)(ws + O_B);        // reuse: x1 dead after scatter
  u16*    ln2q = (u16*)(ws + O_C);          // reuse: x1 dead after scatter
  u16*    gq   = (u16*)(ws + O_G);
  int*    nidx = (int*)(ws + O_IDX);
  float*  szf  = (float*)(ws + O_SZ);
  double2* spart = (double2*)(ws + O_PART);

  float* outf = (float*)d_out;              // f32 output: x then size
  float* szo  = outf + 3145728;

  k_prep<<<27841, 256, 0, stream>>>(qkvw, projw, fc1w, fc2w, qw, pw, f1w_, f2w_, wkT);
  k_ln1<<<8192, 256, 0, stream>>>(x, ln1w, ln1b, h16);
  k_metric64<<<2048, 256, 0, stream>>>(x, ln1w, ln1b, wkT, mn);
  k_scores_tile<<<512, 256, 0, stream>>>(mn, spart);
  k_scores_red<<<16, 256, 0, stream>>>(spart, nidx);
  k_gemm<0><<<dim3(64, 18), 256, 0, stream>>>(h16, qw, 8192, 2304, 768,
      nullptr, nullptr, Qb, Kb, Vb, nullptr);
  k_attn<<<1536, 256, 0, stream>>>(Qb, Kb, Vb, asz, xab);
  k_gemm<1><<<dim3(64, 6), 256, 0, stream>>>(xab, pw, 8192, 768, 768,
      projb, x, nullptr, nullptr, nullptr, x1);
  k_merge_init<<<4096, 256, 0, stream>>>(x1, asz, xm, szf);
  k_merge_scatter<<<4096, 256, 0, stream>>>(x1, asz, nidx, xm, szf);
  k_ln2div<<<4096, 256, 0, stream>>>(xm, szf, ln2w, ln2b, x2, ln2q, szo);
  k_gemm<2><<<dim3(32, 24), 256, 0, stream>>>(ln2q, f1w_, 4096, 3072, 768,
      fc1b, nullptr, gq, nullptr, nullptr, nullptr);
  k_gemm<3><<<dim3(32, 6), 256, 0, stream>>>(gq, f2w_, 4096, 768, 3072,
      fc2b, x2, nullptr, nullptr, nullptr, outf);
}